// Round 1
// baseline (1069.844 us; speedup 1.0000x reference)
//
#include <hip/hip_runtime.h>

constexpr int NN  = 50000;   // nodes
constexpr int NE  = 800000;  // edges
constexpr int HID = 128;

// ---------------------------------------------------------------------------
// Generic register-tiled fp32 GEMM: C[M x 128cols-per-ytile] = A[M x K] @ W[K x N]
// BN = 128 per blockIdx.y tile, BK = 64, 256 threads, micro-tile TM x 8.
// EPI_BIAS: C = acc + bias
// EPI_LAYER: bundle = acc + bias; C = resid + relu(bundle)/max(||bundle||,eps)
// A may be split at k = kSplit between A0 and A1 (concat(h, c) without copy).
// ---------------------------------------------------------------------------
enum { EPI_BIAS = 0, EPI_LAYER = 1 };

template<int BM, int TM, int EPI>
__launch_bounds__(256, 2)
__global__ void gemm_k(const float* __restrict__ A0, const float* __restrict__ A1,
                       int lda, int kSplit,
                       const float* __restrict__ W, int ldw,
                       const float* __restrict__ bias,
                       float* __restrict__ C, int ldc,
                       const float* __restrict__ resid,
                       int M, int K)
{
    static_assert(BM == TM * 16, "bad tile");
    constexpr int BK = 64;
    constexpr int TN = 8;
    __shared__ float As[BK][BM + 4];                     // transposed: As[k][m]
    __shared__ float Ws[BK][128];
    __shared__ float part[(EPI == EPI_LAYER) ? BM : 1][17];
    __shared__ float rinv[(EPI == EPI_LAYER) ? BM : 1];

    const int t  = threadIdx.x;
    const int tm = t >> 4;          // 0..15 row group
    const int tn = t & 15;          // 0..15 col group
    const int by = blockIdx.y;
    W    += (size_t)by * 128;
    bias += (size_t)by * 128;
    C    += (size_t)by * 128;
    const int m0 = blockIdx.x * BM;

    float acc[TM][TN];
#pragma unroll
    for (int i = 0; i < TM; ++i)
#pragma unroll
        for (int j = 0; j < TN; ++j) acc[i][j] = 0.f;

    for (int kt = 0; kt < K; kt += BK) {
        const float* Asrc = (kt < kSplit) ? A0 : A1;
        const int kcol    = (kt < kSplit) ? kt : (kt - kSplit);
        // ---- A tile: BM x 64, load f4 rows, store transposed ----
#pragma unroll
        for (int p = 0; p < BM / 16; ++p) {
            int rl = p * 16 + (t >> 4);
            int gm = m0 + rl;
            int kk = (t & 15) * 4;
            float4 v = make_float4(0.f, 0.f, 0.f, 0.f);
            if (gm < M) v = *(const float4*)&Asrc[(size_t)gm * lda + kcol + kk];
            As[kk + 0][rl] = v.x; As[kk + 1][rl] = v.y;
            As[kk + 2][rl] = v.z; As[kk + 3][rl] = v.w;
        }
        // ---- W tile: 64 x 128 ----
#pragma unroll
        for (int p = 0; p < 8; ++p) {
            int kr = p * 8 + (t >> 5);
            int nc = (t & 31) * 4;
            *(float4*)&Ws[kr][nc] = *(const float4*)&W[(size_t)(kt + kr) * ldw + nc];
        }
        __syncthreads();
#pragma unroll 8
        for (int k = 0; k < BK; ++k) {
            float a[TM], wv[TN];
            if constexpr (TM == 8) {
                float4 x0 = *(const float4*)&As[k][tm * 8];
                float4 x1 = *(const float4*)&As[k][tm * 8 + 4];
                a[0]=x0.x; a[1]=x0.y; a[2]=x0.z; a[3]=x0.w;
                a[4]=x1.x; a[5]=x1.y; a[6]=x1.z; a[7]=x1.w;
            } else {
                float4 x0 = *(const float4*)&As[k][tm * 4];
                a[0]=x0.x; a[1]=x0.y; a[2]=x0.z; a[3]=x0.w;
            }
            float4 w0 = *(const float4*)&Ws[k][tn * 8];
            float4 w1 = *(const float4*)&Ws[k][tn * 8 + 4];
            wv[0]=w0.x; wv[1]=w0.y; wv[2]=w0.z; wv[3]=w0.w;
            wv[4]=w1.x; wv[5]=w1.y; wv[6]=w1.z; wv[7]=w1.w;
#pragma unroll
            for (int i = 0; i < TM; ++i)
#pragma unroll
                for (int j = 0; j < TN; ++j) acc[i][j] += a[i] * wv[j];
        }
        __syncthreads();
    }

    float4 bv0 = *(const float4*)&bias[tn * 8];
    float4 bv1 = *(const float4*)&bias[tn * 8 + 4];
    float bb[8] = {bv0.x, bv0.y, bv0.z, bv0.w, bv1.x, bv1.y, bv1.z, bv1.w};

    if constexpr (EPI == EPI_BIAS) {
#pragma unroll
        for (int i = 0; i < TM; ++i) {
            int gm = m0 + tm * TM + i;
            if (gm < M) {
                float4 o0, o1;
                o0.x = acc[i][0] + bb[0]; o0.y = acc[i][1] + bb[1];
                o0.z = acc[i][2] + bb[2]; o0.w = acc[i][3] + bb[3];
                o1.x = acc[i][4] + bb[4]; o1.y = acc[i][5] + bb[5];
                o1.z = acc[i][6] + bb[6]; o1.w = acc[i][7] + bb[7];
                *(float4*)&C[(size_t)gm * ldc + tn * 8]     = o0;
                *(float4*)&C[(size_t)gm * ldc + tn * 8 + 4] = o1;
            }
        }
    } else {
        // bias add + per-row squared-sum partials
#pragma unroll
        for (int i = 0; i < TM; ++i) {
            float s = 0.f;
#pragma unroll
            for (int j = 0; j < TN; ++j) {
                acc[i][j] += bb[j];
                s += acc[i][j] * acc[i][j];
            }
            part[tm * TM + i][tn] = s;
        }
        __syncthreads();
        if (t < BM) {
            float s = 0.f;
#pragma unroll
            for (int c = 0; c < 16; ++c) s += part[t][c];
            rinv[t] = 1.0f / fmaxf(sqrtf(s), 1e-12f);
        }
        __syncthreads();
#pragma unroll
        for (int i = 0; i < TM; ++i) {
            int gm = m0 + tm * TM + i;
            if (gm < M) {
                float r = rinv[tm * TM + i];
                float4 h0 = *(const float4*)&resid[(size_t)gm * 128 + tn * 8];
                float4 h1 = *(const float4*)&resid[(size_t)gm * 128 + tn * 8 + 4];
                float4 o0, o1;
                o0.x = h0.x + fmaxf(acc[i][0], 0.f) * r;
                o0.y = h0.y + fmaxf(acc[i][1], 0.f) * r;
                o0.z = h0.z + fmaxf(acc[i][2], 0.f) * r;
                o0.w = h0.w + fmaxf(acc[i][3], 0.f) * r;
                o1.x = h1.x + fmaxf(acc[i][4], 0.f) * r;
                o1.y = h1.y + fmaxf(acc[i][5], 0.f) * r;
                o1.z = h1.z + fmaxf(acc[i][6], 0.f) * r;
                o1.w = h1.w + fmaxf(acc[i][7], 0.f) * r;
                *(float4*)&C[(size_t)gm * ldc + tn * 8]     = o0;
                *(float4*)&C[(size_t)gm * ldc + tn * 8 + 4] = o1;
            }
        }
    }
}

// ---------------------------------------------------------------------------
// CSR construction
// ---------------------------------------------------------------------------
__global__ void deg_k(const int* __restrict__ dst, int* __restrict__ deg) {
    int e = blockIdx.x * 256 + threadIdx.x;
    if (e < NE) atomicAdd(&deg[dst[e]], 1);
}

__global__ void scan1_k(const int* __restrict__ deg, int* __restrict__ rp,
                        int* __restrict__ bsum) {
    __shared__ int sh[512];
    int tid = threadIdx.x;
    int i = blockIdx.x * 512 + tid;
    int v = (i < NN) ? deg[i] : 0;
    sh[tid] = v;
    __syncthreads();
    for (int ofs = 1; ofs < 512; ofs <<= 1) {
        int x = (tid >= ofs) ? sh[tid - ofs] : 0;
        __syncthreads();
        sh[tid] += x;
        __syncthreads();
    }
    if (i < NN) rp[i] = sh[tid] - v;            // exclusive
    if (tid == 511) bsum[blockIdx.x] = sh[511]; // block total
}

__global__ void scan2_k(int* __restrict__ bsum, int nb) {
    __shared__ int sh[128];
    int tid = threadIdx.x;
    int v = (tid < nb) ? bsum[tid] : 0;
    sh[tid] = v;
    __syncthreads();
    for (int ofs = 1; ofs < 128; ofs <<= 1) {
        int x = (tid >= ofs) ? sh[tid - ofs] : 0;
        __syncthreads();
        sh[tid] += x;
        __syncthreads();
    }
    if (tid < nb) bsum[tid] = sh[tid] - v;      // exclusive
}

__global__ void scan3_k(int* __restrict__ rp, const int* __restrict__ bsum,
                        const int* __restrict__ deg, float* __restrict__ invd) {
    int i = blockIdx.x * 512 + threadIdx.x;
    if (i < NN) {
        rp[i] += bsum[blockIdx.x];
        int d = deg[i];
        invd[i] = 1.0f / (float)(d > 1 ? d : 1);
    }
    if (i == NN) rp[NN] = NE;
}

__global__ void fill_k(const int* __restrict__ src, const int* __restrict__ dst,
                       const int* __restrict__ rp, int* __restrict__ cnt,
                       int* __restrict__ srt) {
    int e = blockIdx.x * 256 + threadIdx.x;
    if (e < NE) {
        int d = dst[e];
        int pos = atomicAdd(&cnt[d], 1);
        srt[rp[d] + pos] = src[e];
    }
}

// ---------------------------------------------------------------------------
// Mean aggregation: c[n][f] = invd[n] * sum_{j in in(n)} h[src_j][f]
// 1 block (128 thr) per node; srt index is wave-uniform -> scalar loads.
// ---------------------------------------------------------------------------
__global__ void agg_k(const float* __restrict__ h, const int* __restrict__ rp,
                      const int* __restrict__ srt, const float* __restrict__ invd,
                      float* __restrict__ c) {
    int n = blockIdx.x;
    int f = threadIdx.x;
    int b = rp[n], e = rp[n + 1];
    float acc = 0.f;
    for (int j = b; j < e; ++j) acc += h[(size_t)srt[j] * HID + f];
    c[(size_t)n * HID + f] = acc * invd[n];
}

// ---------------------------------------------------------------------------
// Build Weff[k][j] (128 x 256): j<128 -> W0[k][j] (p-half, bias b0),
// j>=128 -> W0[128+k][j-128] (q-half, bias 0). p/q factoring of the edge MLP0.
// ---------------------------------------------------------------------------
__global__ void weff_k(const float* __restrict__ W0, const float* __restrict__ b0,
                       float* __restrict__ Weff, float* __restrict__ beff) {
    int i = blockIdx.x * 256 + threadIdx.x;   // 128*256 = 32768 exact
    int k = i >> 8, j = i & 255;
    Weff[i] = (j < 128) ? W0[k * 128 + j] : W0[(128 + k) * 128 + (j - 128)];
    if (i < 256) beff[i] = (i < 128) ? b0[i] : 0.f;
}

// ---------------------------------------------------------------------------
// Fused edge readout: e0 = relu(p[src]+q[dst]); e1 = relu(e0@W1+b1);
// out = e1@W2+b2.  64 edges/block, W1+b1 in LDS, e0/e1 staged transposed
// ([k][edge]) so phase-2 inner loop is 2x ds_read_b128 per 16 FMA.
// ---------------------------------------------------------------------------
__launch_bounds__(256, 2)
__global__ void edge_mlp_k(const float* __restrict__ pq,
                           const int* __restrict__ esrc, const int* __restrict__ edst,
                           const float* __restrict__ W1, const float* __restrict__ b1,
                           const float* __restrict__ W2, const float* __restrict__ b2,
                           float* __restrict__ out)
{
    __shared__ float W1s[128][64];
    __shared__ float e0t[128][68];   // [k][edge], reused as e1t[o][edge] (stride 68)
    __shared__ float b1s[64];
    __shared__ float W2s[128];       // [o][c] flat
    __shared__ int ss[64], dd[64];
    const int t = threadIdx.x;

#pragma unroll
    for (int p = 0; p < 8; ++p) {    // 2048 float4 = W1 (128x64)
        int i4 = p * 256 + t;
        *(float4*)&W1s[i4 >> 4][(i4 & 15) * 4] = *(const float4*)&W1[(size_t)i4 * 4];
    }
    if (t < 64)  b1s[t] = b1[t];
    if (t < 128) W2s[t] = W2[t];
    const int e0 = blockIdx.x * 64;
    if (t < 64) { ss[t] = esrc[e0 + t]; dd[t] = edst[e0 + t]; }
    __syncthreads();

    // phase 1: gather p[src], q[dst], relu(p+q) -> e0t transposed
#pragma unroll
    for (int p = 0; p < 2; ++p) {
        int ei = p * 32 + (t >> 3);
        int sl = t & 7;
        const float4* pr = (const float4*)&pq[(size_t)ss[ei] * 256];
        const float4* qr = (const float4*)&pq[(size_t)dd[ei] * 256 + 128];
#pragma unroll
        for (int j = 0; j < 4; ++j) {
            int idx = j * 8 + sl;                 // float4 index 0..31
            float4 a = pr[idx], b = qr[idx];
            float4 r;
            r.x = fmaxf(a.x + b.x, 0.f); r.y = fmaxf(a.y + b.y, 0.f);
            r.z = fmaxf(a.z + b.z, 0.f); r.w = fmaxf(a.w + b.w, 0.f);
            int k = idx * 4;
            e0t[k + 0][ei] = r.x; e0t[k + 1][ei] = r.y;
            e0t[k + 2][ei] = r.z; e0t[k + 3][ei] = r.w;
        }
    }
    __syncthreads();

    // phase 2: MLP1, thread = 4 edges x 4 outs
    const int tm = t >> 4, tn = t & 15;
    float acc[4][4];
#pragma unroll
    for (int i = 0; i < 4; ++i)
#pragma unroll
        for (int j = 0; j < 4; ++j) acc[i][j] = 0.f;
#pragma unroll 4
    for (int k = 0; k < 128; ++k) {
        float4 av = *(const float4*)&e0t[k][tm * 4];
        float4 wv = *(const float4*)&W1s[k][tn * 4];
        float a[4] = {av.x, av.y, av.z, av.w};
        float w[4] = {wv.x, wv.y, wv.z, wv.w};
#pragma unroll
        for (int i = 0; i < 4; ++i)
#pragma unroll
            for (int j = 0; j < 4; ++j) acc[i][j] += a[i] * w[j];
    }
    __syncthreads();                 // all e0t reads done before reuse
    float* e1t = &e0t[0][0];
#pragma unroll
    for (int j = 0; j < 4; ++j)
#pragma unroll
        for (int i = 0; i < 4; ++i) {
            float v = fmaxf(acc[i][j] + b1s[tn * 4 + j], 0.f);
            e1t[(size_t)(tn * 4 + j) * 68 + tm * 4 + i] = v;
        }
    __syncthreads();

    // phase 3: MLP2 (64 -> 2)
    if (t < 128) {
        int e = t >> 1, cc = t & 1;
        float s = b2[cc];
#pragma unroll 8
        for (int o = 0; o < 64; ++o) s += e1t[(size_t)o * 68 + e] * W2s[o * 2 + cc];
        out[(size_t)(e0 + e) * 2 + cc] = s;
    }
}

// ---------------------------------------------------------------------------
extern "C" void kernel_launch(void* const* d_in, const int* in_sizes, int n_in,
                              void* d_out, int out_size, void* d_ws, size_t ws_size,
                              hipStream_t stream)
{
    const float* x    = (const float*)d_in[0];
    const int*   esrc = (const int*)  d_in[1];
    const int*   edst = (const int*)  d_in[2];
    // d_in[3] snorm_n, d_in[4] snorm_e: unused by reference
    const float* Wemb  = (const float*)d_in[5];
    const float* bemb  = (const float*)d_in[6];
    const float* Wconv = (const float*)d_in[7];   // [4][256][128]
    const float* bconv = (const float*)d_in[8];   // [4][128]
    const float* Wm0   = (const float*)d_in[9];   // [256][128]
    const float* bm0   = (const float*)d_in[10];  // [128]
    const float* Wm1   = (const float*)d_in[11];  // [128][64]
    const float* bm1   = (const float*)d_in[12];  // [64]
    const float* Wm2   = (const float*)d_in[13];  // [64][2]
    const float* bm2   = (const float*)d_in[14];  // [2]
    float* out = (float*)d_out;

    char* ws = (char*)d_ws;
    size_t off = 0;
    auto alloc = [&](size_t bytes) -> void* {
        void* p = ws + off;
        off = (off + bytes + 255) & ~(size_t)255;
        return p;
    };
    float* h0   = (float*)alloc((size_t)NN * 128 * 4);   // 25.6 MB (256-aligned size)
    float* h1   = (float*)alloc((size_t)NN * 128 * 4);
    float* cbuf = (float*)alloc((size_t)NN * 128 * 4);
    float* pqb  = h1;  // pq [NN][256] overlays h1+cbuf (contiguous, both dead then)
    float* Weff = (float*)alloc(128 * 256 * 4);
    float* beff = (float*)alloc(256 * 4);
    int*   deg  = (int*)alloc((size_t)NN * 4);
    int*   rp   = (int*)alloc((size_t)(NN + 1) * 4);
    int*   cnt  = (int*)alloc((size_t)NN * 4);
    float* invd = (float*)alloc((size_t)NN * 4);
    int*   bsum = (int*)alloc(512);
    int*   srt  = (int*)alloc((size_t)NE * 4);
    (void)ws_size; (void)in_sizes; (void)n_in; (void)out_size; (void)bsum;

    hipMemsetAsync(deg, 0, (size_t)NN * 4, stream);
    hipMemsetAsync(cnt, 0, (size_t)NN * 4, stream);

    // h0 = x @ Wemb + bemb
    gemm_k<64, 4, EPI_BIAS><<<dim3((NN + 63) / 64, 1), 256, 0, stream>>>(
        x, nullptr, 64, 1 << 30, Wemb, 128, bemb, h0, 128, nullptr, NN, 64);

    // CSR build
    deg_k  <<<(NE + 255) / 256, 256, 0, stream>>>(edst, deg);
    scan1_k<<<(NN + 511) / 512, 512, 0, stream>>>(deg, rp, bsum);
    scan2_k<<<1, 128, 0, stream>>>(bsum, (NN + 511) / 512);
    scan3_k<<<(NN + 511) / 512, 512, 0, stream>>>(rp, bsum, deg, invd);
    fill_k <<<(NE + 255) / 256, 256, 0, stream>>>(esrc, edst, rp, cnt, srt);

    // 4 SAGE layers
    float* hc = h0; float* hn = h1;
    for (int l = 0; l < 4; ++l) {
        agg_k<<<NN, 128, 0, stream>>>(hc, rp, srt, invd, cbuf);
        gemm_k<128, 8, EPI_LAYER><<<dim3((NN + 127) / 128, 1), 256, 0, stream>>>(
            hc, cbuf, 128, 128, Wconv + (size_t)l * 256 * 128, 128,
            bconv + (size_t)l * 128, hn, 128, hc, NN, 256);
        float* tmp = hc; hc = hn; hn = tmp;
    }
    // after an even number of layers, hc == h0 (doesn't alias pqb)

    // edge readout: pq = h @ Weff (+beff), then fused per-edge MLP
    weff_k<<<128, 256, 0, stream>>>(Wm0, bm0, Weff, beff);
    gemm_k<128, 8, EPI_BIAS><<<dim3((NN + 127) / 128, 2), 256, 0, stream>>>(
        hc, nullptr, 128, 1 << 30, Weff, 256, beff, pqb, 256, nullptr, NN, 128);
    edge_mlp_k<<<NE / 64, 256, 0, stream>>>(pqb, esrc, edst, Wm1, bm1, Wm2, bm2, out);
}

// Round 2
// 734.308 us; speedup vs baseline: 1.4569x; 1.4569x over previous
//
#include <hip/hip_runtime.h>

constexpr int NN  = 50000;   // nodes
constexpr int NE  = 800000;  // edges

using frag_ab = __attribute__((ext_vector_type(8))) short;  // 8 bf16
using frag_cd = __attribute__((ext_vector_type(4))) float;  // 4 fp32

__device__ __forceinline__ unsigned short f2bf(float f) {
    union { float f; unsigned u; } v; v.f = f;
    unsigned r = v.u + 0x7FFFu + ((v.u >> 16) & 1u);   // RNE
    return (unsigned short)(r >> 16);
}
__device__ __forceinline__ float bflo(unsigned u) {
    union { unsigned u; float f; } v; v.u = u << 16; return v.f;
}
__device__ __forceinline__ float bfhi(unsigned u) {
    union { unsigned u; float f; } v; v.u = u & 0xFFFF0000u; return v.f;
}
__device__ __forceinline__ unsigned packbf(float a, float b) {
    return (unsigned)f2bf(a) | ((unsigned)f2bf(b) << 16);
}

// ---------------------------------------------------------------------------
// Register-tiled fp32 GEMM. C[M x 128-per-ytile] = A[M x K] @ W[K x N].
// EPI_BIAS : C = acc + bias (fp32), optional bf16 mirror (stride 128)
// EPI_LAYER: bundle = acc+bias; C = resid + relu(bundle)/max(||bundle||,eps),
//            optional bf16 mirror (stride 128)
// EPI_PQBF : write bf16 only to Cbf (row stride ldc, col offset by*128)
// A split at k = kSplit between A0 and A1 (concat(h, c) without copy).
// ---------------------------------------------------------------------------
enum { EPI_BIAS = 0, EPI_LAYER = 1, EPI_PQBF = 2 };

template<int BM, int TM, int EPI, bool MIRROR>
__launch_bounds__(256, 2)
__global__ void gemm_k(const float* __restrict__ A0, const float* __restrict__ A1,
                       int lda, int kSplit,
                       const float* __restrict__ W, int ldw,
                       const float* __restrict__ bias,
                       float* __restrict__ C, unsigned short* __restrict__ Cbf,
                       int ldc,
                       const float* __restrict__ resid,
                       int M, int K)
{
    static_assert(BM == TM * 16, "bad tile");
    constexpr int BK = 64;
    constexpr int TN = 8;
    __shared__ float As[BK][BM + 4];                     // transposed: As[k][m]
    __shared__ float Ws[BK][128];
    __shared__ float part[(EPI == EPI_LAYER) ? BM : 1][17];
    __shared__ float rinv[(EPI == EPI_LAYER) ? BM : 1];

    const int t  = threadIdx.x;
    const int tm = t >> 4;
    const int tn = t & 15;
    const int by = blockIdx.y;
    W    += (size_t)by * 128;
    bias += (size_t)by * 128;
    C    += (size_t)by * 128;
    if (Cbf) Cbf += (size_t)by * 128;
    const int m0 = blockIdx.x * BM;

    float acc[TM][TN];
#pragma unroll
    for (int i = 0; i < TM; ++i)
#pragma unroll
        for (int j = 0; j < TN; ++j) acc[i][j] = 0.f;

    for (int kt = 0; kt < K; kt += BK) {
        const float* Asrc = (kt < kSplit) ? A0 : A1;
        const int kcol    = (kt < kSplit) ? kt : (kt - kSplit);
#pragma unroll
        for (int p = 0; p < BM / 16; ++p) {
            int rl = p * 16 + (t >> 4);
            int gm = m0 + rl;
            int kk = (t & 15) * 4;
            float4 v = make_float4(0.f, 0.f, 0.f, 0.f);
            if (gm < M) v = *(const float4*)&Asrc[(size_t)gm * lda + kcol + kk];
            As[kk + 0][rl] = v.x; As[kk + 1][rl] = v.y;
            As[kk + 2][rl] = v.z; As[kk + 3][rl] = v.w;
        }
#pragma unroll
        for (int p = 0; p < 8; ++p) {
            int kr = p * 8 + (t >> 5);
            int nc = (t & 31) * 4;
            *(float4*)&Ws[kr][nc] = *(const float4*)&W[(size_t)(kt + kr) * ldw + nc];
        }
        __syncthreads();
#pragma unroll 8
        for (int k = 0; k < BK; ++k) {
            float a[TM], wv[TN];
            if constexpr (TM == 8) {
                float4 x0 = *(const float4*)&As[k][tm * 8];
                float4 x1 = *(const float4*)&As[k][tm * 8 + 4];
                a[0]=x0.x; a[1]=x0.y; a[2]=x0.z; a[3]=x0.w;
                a[4]=x1.x; a[5]=x1.y; a[6]=x1.z; a[7]=x1.w;
            } else {
                float4 x0 = *(const float4*)&As[k][tm * 4];
                a[0]=x0.x; a[1]=x0.y; a[2]=x0.z; a[3]=x0.w;
            }
            float4 w0 = *(const float4*)&Ws[k][tn * 8];
            float4 w1 = *(const float4*)&Ws[k][tn * 8 + 4];
            wv[0]=w0.x; wv[1]=w0.y; wv[2]=w0.z; wv[3]=w0.w;
            wv[4]=w1.x; wv[5]=w1.y; wv[6]=w1.z; wv[7]=w1.w;
#pragma unroll
            for (int i = 0; i < TM; ++i)
#pragma unroll
                for (int j = 0; j < TN; ++j) acc[i][j] += a[i] * wv[j];
        }
        __syncthreads();
    }

    float4 bv0 = *(const float4*)&bias[tn * 8];
    float4 bv1 = *(const float4*)&bias[tn * 8 + 4];
    float bb[8] = {bv0.x, bv0.y, bv0.z, bv0.w, bv1.x, bv1.y, bv1.z, bv1.w};

    if constexpr (EPI == EPI_LAYER) {
#pragma unroll
        for (int i = 0; i < TM; ++i) {
            float s = 0.f;
#pragma unroll
            for (int j = 0; j < TN; ++j) {
                acc[i][j] += bb[j];
                s += acc[i][j] * acc[i][j];
            }
            part[tm * TM + i][tn] = s;
        }
        __syncthreads();
        if (t < BM) {
            float s = 0.f;
#pragma unroll
            for (int c = 0; c < 16; ++c) s += part[t][c];
            rinv[t] = 1.0f / fmaxf(sqrtf(s), 1e-12f);
        }
        __syncthreads();
    }

#pragma unroll
    for (int i = 0; i < TM; ++i) {
        int gm = m0 + tm * TM + i;
        if (gm >= M) continue;
        float o[8];
        if constexpr (EPI == EPI_LAYER) {
            float r = rinv[tm * TM + i];
            float4 h0 = *(const float4*)&resid[(size_t)gm * 128 + tn * 8];
            float4 h1 = *(const float4*)&resid[(size_t)gm * 128 + tn * 8 + 4];
            o[0] = h0.x + fmaxf(acc[i][0], 0.f) * r;
            o[1] = h0.y + fmaxf(acc[i][1], 0.f) * r;
            o[2] = h0.z + fmaxf(acc[i][2], 0.f) * r;
            o[3] = h0.w + fmaxf(acc[i][3], 0.f) * r;
            o[4] = h1.x + fmaxf(acc[i][4], 0.f) * r;
            o[5] = h1.y + fmaxf(acc[i][5], 0.f) * r;
            o[6] = h1.z + fmaxf(acc[i][6], 0.f) * r;
            o[7] = h1.w + fmaxf(acc[i][7], 0.f) * r;
        } else {
#pragma unroll
            for (int j = 0; j < 8; ++j) o[j] = acc[i][j] + bb[j];
        }
        if constexpr (EPI != EPI_PQBF) {
            float4 o0 = make_float4(o[0], o[1], o[2], o[3]);
            float4 o1 = make_float4(o[4], o[5], o[6], o[7]);
            *(float4*)&C[(size_t)gm * ldc + tn * 8]     = o0;
            *(float4*)&C[(size_t)gm * ldc + tn * 8 + 4] = o1;
            if constexpr (MIRROR) {
                uint4 mv = make_uint4(packbf(o[0], o[1]), packbf(o[2], o[3]),
                                      packbf(o[4], o[5]), packbf(o[6], o[7]));
                *(uint4*)&Cbf[(size_t)gm * 128 + tn * 8] = mv;
            }
        } else {
            uint4 mv = make_uint4(packbf(o[0], o[1]), packbf(o[2], o[3]),
                                  packbf(o[4], o[5]), packbf(o[6], o[7]));
            *(uint4*)&Cbf[(size_t)gm * ldc + tn * 8] = mv;
        }
    }
}

// ---------------------------------------------------------------------------
// CSR construction
// ---------------------------------------------------------------------------
__global__ void deg_k(const int* __restrict__ dst, int* __restrict__ deg) {
    int e = blockIdx.x * 256 + threadIdx.x;
    if (e < NE) atomicAdd(&deg[dst[e]], 1);
}

__global__ void scan1_k(const int* __restrict__ deg, int* __restrict__ rp,
                        int* __restrict__ bsum) {
    __shared__ int sh[512];
    int tid = threadIdx.x;
    int i = blockIdx.x * 512 + tid;
    int v = (i < NN) ? deg[i] : 0;
    sh[tid] = v;
    __syncthreads();
    for (int ofs = 1; ofs < 512; ofs <<= 1) {
        int x = (tid >= ofs) ? sh[tid - ofs] : 0;
        __syncthreads();
        sh[tid] += x;
        __syncthreads();
    }
    if (i < NN) rp[i] = sh[tid] - v;
    if (tid == 511) bsum[blockIdx.x] = sh[511];
}

__global__ void scan2_k(int* __restrict__ bsum, int nb) {
    __shared__ int sh[128];
    int tid = threadIdx.x;
    int v = (tid < nb) ? bsum[tid] : 0;
    sh[tid] = v;
    __syncthreads();
    for (int ofs = 1; ofs < 128; ofs <<= 1) {
        int x = (tid >= ofs) ? sh[tid - ofs] : 0;
        __syncthreads();
        sh[tid] += x;
        __syncthreads();
    }
    if (tid < nb) bsum[tid] = sh[tid] - v;
}

__global__ void scan3_k(int* __restrict__ rp, const int* __restrict__ bsum,
                        const int* __restrict__ deg, float* __restrict__ invd) {
    int i = blockIdx.x * 512 + threadIdx.x;
    if (i < NN) {
        rp[i] += bsum[blockIdx.x];
        int d = deg[i];
        invd[i] = 1.0f / (float)(d > 1 ? d : 1);
    }
    if (i == NN) rp[NN] = NE;
}

__global__ void fill_k(const int* __restrict__ src, const int* __restrict__ dst,
                       const int* __restrict__ rp, int* __restrict__ cnt,
                       int* __restrict__ srt) {
    int e = blockIdx.x * 256 + threadIdx.x;
    if (e < NE) {
        int d = dst[e];
        int pos = atomicAdd(&cnt[d], 1);
        srt[rp[d] + pos] = src[e];
    }
}

// ---------------------------------------------------------------------------
// Mean aggregation, one WAVE per node, bf16 h rows (256 B), dword per lane.
// 4-neighbor unroll for ILP; accumulate fp32; c written fp32.
// ---------------------------------------------------------------------------
__launch_bounds__(256, 8)
__global__ void agg_k(const unsigned short* __restrict__ hbf,
                      const int* __restrict__ rp, const int* __restrict__ srt,
                      const float* __restrict__ invd, float* __restrict__ c) {
    int gw   = (blockIdx.x * 256 + threadIdx.x) >> 6;   // node = global wave id
    int lane = threadIdx.x & 63;
    if (gw >= NN) return;
    int b = rp[gw], e = rp[gw + 1];
    float a0 = 0.f, a1 = 0.f;
    int j = b;
    for (; j + 4 <= e; j += 4) {
        int s0 = srt[j], s1 = srt[j + 1], s2 = srt[j + 2], s3 = srt[j + 3];
        unsigned u0 = *(const unsigned*)&hbf[(size_t)s0 * 128 + lane * 2];
        unsigned u1 = *(const unsigned*)&hbf[(size_t)s1 * 128 + lane * 2];
        unsigned u2 = *(const unsigned*)&hbf[(size_t)s2 * 128 + lane * 2];
        unsigned u3 = *(const unsigned*)&hbf[(size_t)s3 * 128 + lane * 2];
        a0 += bflo(u0) + bflo(u1) + bflo(u2) + bflo(u3);
        a1 += bfhi(u0) + bfhi(u1) + bfhi(u2) + bfhi(u3);
    }
    for (; j < e; ++j) {
        unsigned u = *(const unsigned*)&hbf[(size_t)srt[j] * 128 + lane * 2];
        a0 += bflo(u); a1 += bfhi(u);
    }
    float iv = invd[gw];
    *(float2*)&c[(size_t)gw * 128 + lane * 2] = make_float2(a0 * iv, a1 * iv);
}

// ---------------------------------------------------------------------------
// Prep: Weff[k][j] (128x256) p/q factoring of edge MLP0, beff, and W1
// transposed to bf16 global [64][128] (B-operand-friendly).
// ---------------------------------------------------------------------------
__global__ void weff_k(const float* __restrict__ W0, const float* __restrict__ b0,
                       const float* __restrict__ W1,
                       float* __restrict__ Weff, float* __restrict__ beff,
                       unsigned short* __restrict__ W1tg) {
    int i = blockIdx.x * 256 + threadIdx.x;   // 128*256 = 32768 exact
    int k = i >> 8, j = i & 255;
    Weff[i] = (j < 128) ? W0[k * 128 + j] : W0[(128 + k) * 128 + (j - 128)];
    if (i < 256) beff[i] = (i < 128) ? b0[i] : 0.f;
    if (i < 8192) {                            // W1tg[n][k] = bf16(W1[k][n])
        int n = i >> 7, kk = i & 127;
        W1tg[i] = f2bf(W1[kk * 64 + n]);
    }
}

// ---------------------------------------------------------------------------
// Fused edge readout, MFMA version.
// e0 = relu(p[src]+q[dst]) in bf16; e1 = relu(e0 @ W1 + b1) via
// mfma_f32_16x16x32_bf16 (4 waves x 16 edges x 64 outs); out = e1 @ W2 + b2.
// 64 edges/block. e1t overlays W1s after MFMA to keep LDS at 36 KB (4 blk/CU).
// ---------------------------------------------------------------------------
__launch_bounds__(256, 4)
__global__ void edge_mlp_k(const unsigned short* __restrict__ pq,
                           const int* __restrict__ esrc, const int* __restrict__ edst,
                           const unsigned short* __restrict__ W1tg,
                           const float* __restrict__ b1,
                           const float* __restrict__ W2, const float* __restrict__ b2,
                           float* __restrict__ out)
{
    __shared__ __align__(16) unsigned short E0s[64][136];  // [edge][k], pad 8
    __shared__ __align__(16) unsigned short W1s[64][136];  // [n][k], pad 8
    __shared__ float b1s[64];
    __shared__ float W2s[128];
    __shared__ int ss[64], dd[64];
    const int t = threadIdx.x;
    const int e0 = blockIdx.x * 64;

    // stage W1t (bf16, 16 KB), b1, W2, edge indices
#pragma unroll
    for (int p = 0; p < 4; ++p) {
        int idx = t * 32 + p * 8;               // 8192 ushorts total
        int n = idx >> 7, col = idx & 127;
        *(uint4*)&W1s[n][col] = *(const uint4*)&W1tg[idx];
    }
    if (t < 64)  b1s[t] = b1[t];
    if (t < 128) W2s[t] = W2[t];
    if (t < 64) { ss[t] = esrc[e0 + t]; dd[t] = edst[e0 + t]; }
    __syncthreads();

    // phase 1: gather p[src], q[dst] (bf16), e0 = relu(p+q) -> E0s bf16
    {
        const int ei = t >> 2;                  // 64 edges, 4 thr/edge
        const int fs = (t & 3) * 32;            // 32 features each
        const unsigned short* pr = pq + (size_t)ss[ei] * 256 + fs;
        const unsigned short* qr = pq + (size_t)dd[ei] * 256 + 128 + fs;
#pragma unroll
        for (int j = 0; j < 4; ++j) {           // 8 feats per iter
            uint4 a = *(const uint4*)(pr + j * 8);
            uint4 b = *(const uint4*)(qr + j * 8);
            uint4 r;
            r.x = packbf(fmaxf(bflo(a.x) + bflo(b.x), 0.f),
                         fmaxf(bfhi(a.x) + bfhi(b.x), 0.f));
            r.y = packbf(fmaxf(bflo(a.y) + bflo(b.y), 0.f),
                         fmaxf(bfhi(a.y) + bfhi(b.y), 0.f));
            r.z = packbf(fmaxf(bflo(a.z) + bflo(b.z), 0.f),
                         fmaxf(bfhi(a.z) + bfhi(b.z), 0.f));
            r.w = packbf(fmaxf(bflo(a.w) + bflo(b.w), 0.f),
                         fmaxf(bfhi(a.w) + bfhi(b.w), 0.f));
            *(uint4*)&E0s[ei][fs + j * 8] = r;
        }
    }
    __syncthreads();

    // phase 2: MLP1 via MFMA. wave w handles edges [16w,16w+16) x all 64 outs.
    const int wv = t >> 6;
    const int l  = t & 63;
    const int lq = l >> 4, lm = l & 15;
    frag_cd acc[4];
#pragma unroll
    for (int tb = 0; tb < 4; ++tb) acc[tb] = (frag_cd){0.f, 0.f, 0.f, 0.f};
    const int erow = wv * 16 + lm;
#pragma unroll
    for (int kb = 0; kb < 4; ++kb) {
        frag_ab af = *(const frag_ab*)&E0s[erow][kb * 32 + lq * 8];
#pragma unroll
        for (int tb = 0; tb < 4; ++tb) {
            frag_ab bf = *(const frag_ab*)&W1s[tb * 16 + lm][kb * 32 + lq * 8];
            acc[tb] = __builtin_amdgcn_mfma_f32_16x16x32_bf16(af, bf, acc[tb], 0, 0, 0);
        }
    }
    __syncthreads();                 // all reads of W1s/E0s done

    // epilogue: e1 = relu(acc + b1) -> e1t[out][edge] (overlays W1s)
    float* e1t = (float*)&W1s[0][0];            // [64][68] fp32
#pragma unroll
    for (int tb = 0; tb < 4; ++tb) {
        int o = tb * 16 + lm;                   // C/D: col = lane&15
        float bias = b1s[o];
#pragma unroll
        for (int r = 0; r < 4; ++r) {           // row = (lane>>4)*4 + reg
            int e = wv * 16 + lq * 4 + r;
            e1t[(size_t)o * 68 + e] = fmaxf(acc[tb][r] + bias, 0.f);
        }
    }
    __syncthreads();

    // phase 3: MLP2 (64 -> 2)
    if (t < 128) {
        int e = t >> 1, cc = t & 1;
        float s = b2[cc];
#pragma unroll 8
        for (int o = 0; o < 64; ++o) s += e1t[(size_t)o * 68 + e] * W2s[o * 2 + cc];
        out[(size_t)(e0 + e) * 2 + cc] = s;
    }
}

// ---------------------------------------------------------------------------
extern "C" void kernel_launch(void* const* d_in, const int* in_sizes, int n_in,
                              void* d_out, int out_size, void* d_ws, size_t ws_size,
                              hipStream_t stream)
{
    const float* x    = (const float*)d_in[0];
    const int*   esrc = (const int*)  d_in[1];
    const int*   edst = (const int*)  d_in[2];
    const float* Wemb  = (const float*)d_in[5];
    const float* bemb  = (const float*)d_in[6];
    const float* Wconv = (const float*)d_in[7];
    const float* bconv = (const float*)d_in[8];
    const float* Wm0   = (const float*)d_in[9];
    const float* bm0   = (const float*)d_in[10];
    const float* Wm1   = (const float*)d_in[11];
    const float* bm1   = (const float*)d_in[12];
    const float* Wm2   = (const float*)d_in[13];
    const float* bm2   = (const float*)d_in[14];
    float* out = (float*)d_out;

    char* ws = (char*)d_ws;
    size_t off = 0;
    auto alloc = [&](size_t bytes) -> void* {
        void* p = ws + off;
        off = (off + bytes + 255) & ~(size_t)255;
        return p;
    };
    float*          h0   = (float*)alloc((size_t)NN * 128 * 4);
    float*          h1   = (float*)alloc((size_t)NN * 128 * 4);
    float*          cbuf = (float*)alloc((size_t)NN * 128 * 4);   // also pq (bf16)
    unsigned short* h0bf = (unsigned short*)alloc((size_t)NN * 128 * 2);
    unsigned short* h1bf = (unsigned short*)alloc((size_t)NN * 128 * 2);
    unsigned short* pqb  = (unsigned short*)cbuf;                 // [NN][256] bf16
    float*          Weff = (float*)alloc(128 * 256 * 4);
    float*          beff = (float*)alloc(256 * 4);
    unsigned short* W1tg = (unsigned short*)alloc(64 * 128 * 2);
    int*   deg  = (int*)alloc((size_t)NN * 4);
    int*   rp   = (int*)alloc((size_t)(NN + 1) * 4);
    int*   cnt  = (int*)alloc((size_t)NN * 4);
    float* invd = (float*)alloc((size_t)NN * 4);
    int*   bsum = (int*)alloc(512);
    int*   srt  = (int*)alloc((size_t)NE * 4);
    (void)ws_size; (void)in_sizes; (void)n_in; (void)out_size;

    hipMemsetAsync(deg, 0, (size_t)NN * 4, stream);
    hipMemsetAsync(cnt, 0, (size_t)NN * 4, stream);

    // h0 = x @ Wemb + bemb  (+ bf16 mirror)
    gemm_k<64, 4, EPI_BIAS, true><<<dim3((NN + 63) / 64, 1), 256, 0, stream>>>(
        x, nullptr, 64, 1 << 30, Wemb, 128, bemb, h0, h0bf, 128, nullptr, NN, 64);

    // CSR build
    deg_k  <<<(NE + 255) / 256, 256, 0, stream>>>(edst, deg);
    scan1_k<<<(NN + 511) / 512, 512, 0, stream>>>(deg, rp, bsum);
    scan2_k<<<1, 128, 0, stream>>>(bsum, (NN + 511) / 512);
    scan3_k<<<(NN + 511) / 512, 512, 0, stream>>>(rp, bsum, deg, invd);
    fill_k <<<(NE + 255) / 256, 256, 0, stream>>>(esrc, edst, rp, cnt, srt);

    // prep readout weights (overlaps CSR work)
    weff_k<<<128, 256, 0, stream>>>(Wm0, bm0, Wm1, Weff, beff, W1tg);

    // 4 SAGE layers
    float* hc = h0; float* hn = h1;
    unsigned short* hcbf = h0bf; unsigned short* hnbf = h1bf;
    for (int l = 0; l < 4; ++l) {
        agg_k<<<(NN + 3) / 4, 256, 0, stream>>>(hcbf, rp, srt, invd, cbuf);
        gemm_k<128, 8, EPI_LAYER, true><<<dim3((NN + 127) / 128, 1), 256, 0, stream>>>(
            hc, cbuf, 128, 128, Wconv + (size_t)l * 256 * 128, 128,
            bconv + (size_t)l * 128, hn, hnbf, 128, hc, NN, 256);
        float* tf = hc; hc = hn; hn = tf;
        unsigned short* tb = hcbf; hcbf = hnbf; hnbf = tb;
    }
    // after 4 layers hc == h0 (cbuf free for pq reuse)

    // pq = h @ Weff (+beff) -> bf16 [NN][256]
    gemm_k<128, 8, EPI_PQBF, false><<<dim3((NN + 127) / 128, 2), 256, 0, stream>>>(
        hc, nullptr, 128, 1 << 30, Weff, 256, beff, nullptr, pqb, 256, nullptr, NN, 128);

    // fused edge readout
    edge_mlp_k<<<NE / 64, 256, 0, stream>>>(pqb, esrc, edst, W1tg, bm1, Wm2, bm2, out);
}

// Round 3
// 534.021 us; speedup vs baseline: 2.0034x; 1.3751x over previous
//
#include <hip/hip_runtime.h>

constexpr int NN  = 50000;   // nodes
constexpr int NE  = 800000;  // edges

using frag_ab = __attribute__((ext_vector_type(8))) short;  // 8 bf16
using frag_cd = __attribute__((ext_vector_type(4))) float;  // 4 fp32

__device__ __forceinline__ unsigned short f2bf(float f) {
    union { float f; unsigned u; } v; v.f = f;
    unsigned r = v.u + 0x7FFFu + ((v.u >> 16) & 1u);   // RNE
    return (unsigned short)(r >> 16);
}
__device__ __forceinline__ float bflo(unsigned u) {
    union { unsigned u; float f; } v; v.u = u << 16; return v.f;
}
__device__ __forceinline__ float bfhi(unsigned u) {
    union { unsigned u; float f; } v; v.u = u & 0xFFFF0000u; return v.f;
}
__device__ __forceinline__ unsigned packbf(float a, float b) {
    return (unsigned)f2bf(a) | ((unsigned)f2bf(b) << 16);
}

enum { EPI_BIAS = 0, EPI_LAYER = 1, EPI_PQBF = 2 };

// ---------------------------------------------------------------------------
// fp32 register-tiled GEMM — used only for the embed layer (K=64, fp32 x).
// Writes fp32 C + bf16 mirror.
// ---------------------------------------------------------------------------
template<int BM, int TM>
__launch_bounds__(256, 2)
__global__ void gemm_k(const float* __restrict__ A0, int lda,
                       const float* __restrict__ W, int ldw,
                       const float* __restrict__ bias,
                       float* __restrict__ C, unsigned short* __restrict__ Cbf,
                       int ldc, int M, int K)
{
    static_assert(BM == TM * 16, "bad tile");
    constexpr int BK = 64;
    constexpr int TN = 8;
    __shared__ float As[BK][BM + 4];
    __shared__ float Ws[BK][128];

    const int t  = threadIdx.x;
    const int tm = t >> 4;
    const int tn = t & 15;
    const int m0 = blockIdx.x * BM;

    float acc[TM][TN];
#pragma unroll
    for (int i = 0; i < TM; ++i)
#pragma unroll
        for (int j = 0; j < TN; ++j) acc[i][j] = 0.f;

    for (int kt = 0; kt < K; kt += BK) {
#pragma unroll
        for (int p = 0; p < BM / 16; ++p) {
            int rl = p * 16 + (t >> 4);
            int gm = m0 + rl;
            int kk = (t & 15) * 4;
            float4 v = make_float4(0.f, 0.f, 0.f, 0.f);
            if (gm < M) v = *(const float4*)&A0[(size_t)gm * lda + kt + kk];
            As[kk + 0][rl] = v.x; As[kk + 1][rl] = v.y;
            As[kk + 2][rl] = v.z; As[kk + 3][rl] = v.w;
        }
#pragma unroll
        for (int p = 0; p < 8; ++p) {
            int kr = p * 8 + (t >> 5);
            int nc = (t & 31) * 4;
            *(float4*)&Ws[kr][nc] = *(const float4*)&W[(size_t)(kt + kr) * ldw + nc];
        }
        __syncthreads();
#pragma unroll 8
        for (int k = 0; k < BK; ++k) {
            float a[TM], wv[TN];
            float4 x0 = *(const float4*)&As[k][tm * TM];
            a[0]=x0.x; a[1]=x0.y; a[2]=x0.z; a[3]=x0.w;
            float4 w0 = *(const float4*)&Ws[k][tn * 8];
            float4 w1 = *(const float4*)&Ws[k][tn * 8 + 4];
            wv[0]=w0.x; wv[1]=w0.y; wv[2]=w0.z; wv[3]=w0.w;
            wv[4]=w1.x; wv[5]=w1.y; wv[6]=w1.z; wv[7]=w1.w;
#pragma unroll
            for (int i = 0; i < TM; ++i)
#pragma unroll
                for (int j = 0; j < TN; ++j) acc[i][j] += a[i] * wv[j];
        }
        __syncthreads();
    }

    float4 bv0 = *(const float4*)&bias[tn * 8];
    float4 bv1 = *(const float4*)&bias[tn * 8 + 4];
    float bb[8] = {bv0.x, bv0.y, bv0.z, bv0.w, bv1.x, bv1.y, bv1.z, bv1.w};

#pragma unroll
    for (int i = 0; i < TM; ++i) {
        int gm = m0 + tm * TM + i;
        if (gm >= M) continue;
        float o[8];
#pragma unroll
        for (int j = 0; j < 8; ++j) o[j] = acc[i][j] + bb[j];
        *(float4*)&C[(size_t)gm * ldc + tn * 8]     = make_float4(o[0], o[1], o[2], o[3]);
        *(float4*)&C[(size_t)gm * ldc + tn * 8 + 4] = make_float4(o[4], o[5], o[6], o[7]);
        uint4 mv = make_uint4(packbf(o[0], o[1]), packbf(o[2], o[3]),
                              packbf(o[4], o[5]), packbf(o[6], o[7]));
        *(uint4*)&Cbf[(size_t)gm * 128 + tn * 8] = mv;
    }
}

// ---------------------------------------------------------------------------
// MFMA bf16 GEMM: C[M x 128-per-ytile] = A[M x K](bf16) @ Wt[N][K](bf16).
// Block: 64 rows x 128 cols, 4 waves (wave = 16 rows x 128 cols), BK=64.
// EPI_LAYER: bundle = acc+bias; C = resid + relu(bundle)/max(||bundle||,eps)
//            (fp32) + bf16 mirror. A split at kSplit between A0/A1.
// EPI_PQBF : Cbf = bf16(acc + bias), col offset by*128, row stride ldc.
// ---------------------------------------------------------------------------
template<int EPI>
__launch_bounds__(256, 4)
__global__ void mfma_gemm_k(const unsigned short* __restrict__ A0,
                            const unsigned short* __restrict__ A1,
                            int lda, int kSplit,
                            const unsigned short* __restrict__ Wt,
                            const float* __restrict__ bias,
                            float* __restrict__ C,
                            unsigned short* __restrict__ Cbf, int ldc,
                            const float* __restrict__ resid,
                            int M, int K)
{
    __shared__ __align__(16) unsigned short As[64][72];    // [row][k], pad 8
    __shared__ __align__(16) unsigned short Ws[128][72];   // [n][k],  pad 8
    __shared__ float bs[128];
    __shared__ float part[(EPI == EPI_LAYER) ? 64 : 1][17];
    __shared__ float rinv[(EPI == EPI_LAYER) ? 64 : 1];

    const int t  = threadIdx.x;
    const int by = blockIdx.y;
    Wt   += (size_t)by * 128 * K;
    bias += (size_t)by * 128;
    if constexpr (EPI == EPI_PQBF) Cbf += (size_t)by * 128;
    const int m0 = blockIdx.x * 64;

    if (t < 128) bs[t] = bias[t];

    const int wv = t >> 6, l = t & 63, lq = l >> 4, lm = l & 15;
    frag_cd acc[8];
#pragma unroll
    for (int tb = 0; tb < 8; ++tb) acc[tb] = (frag_cd){0.f, 0.f, 0.f, 0.f};

    for (int kt = 0; kt < K; kt += 64) {
        const unsigned short* Asrc = (kt < kSplit) ? A0 : A1;
        const int kcol = (kt < kSplit) ? kt : kt - kSplit;
#pragma unroll
        for (int p = 0; p < 2; ++p) {
            int idx = p * 256 + t;            // 512 uint4 = 64 x 64 bf16
            int row = idx >> 3, c4 = idx & 7;
            int gm = m0 + row;
            uint4 v = make_uint4(0, 0, 0, 0);
            if (gm < M) v = *(const uint4*)&Asrc[(size_t)gm * lda + kcol + c4 * 8];
            *(uint4*)&As[row][c4 * 8] = v;
        }
#pragma unroll
        for (int p = 0; p < 4; ++p) {
            int idx = p * 256 + t;            // 1024 uint4 = 128 x 64 bf16
            int n = idx >> 3, c4 = idx & 7;
            *(uint4*)&Ws[n][c4 * 8] = *(const uint4*)&Wt[(size_t)n * K + kt + c4 * 8];
        }
        __syncthreads();
#pragma unroll
        for (int kb = 0; kb < 2; ++kb) {
            frag_ab af = *(const frag_ab*)&As[wv * 16 + lm][kb * 32 + lq * 8];
#pragma unroll
            for (int tb = 0; tb < 8; ++tb) {
                frag_ab bf = *(const frag_ab*)&Ws[tb * 16 + lm][kb * 32 + lq * 8];
                acc[tb] = __builtin_amdgcn_mfma_f32_16x16x32_bf16(af, bf, acc[tb], 0, 0, 0);
            }
        }
        __syncthreads();
    }

    if constexpr (EPI == EPI_LAYER) {
        float sq[4] = {0.f, 0.f, 0.f, 0.f};
#pragma unroll
        for (int tb = 0; tb < 8; ++tb) {
            float b = bs[tb * 16 + lm];
#pragma unroll
            for (int r = 0; r < 4; ++r) {
                acc[tb][r] += b;
                sq[r] += acc[tb][r] * acc[tb][r];
            }
        }
#pragma unroll
        for (int r = 0; r < 4; ++r) part[wv * 16 + lq * 4 + r][lm] = sq[r];
        __syncthreads();
        if (t < 64) {
            float s = 0.f;
#pragma unroll
            for (int c = 0; c < 16; ++c) s += part[t][c];
            rinv[t] = 1.0f / fmaxf(sqrtf(s), 1e-12f);
        }
        __syncthreads();
#pragma unroll
        for (int r = 0; r < 4; ++r) {
            int gr = m0 + wv * 16 + lq * 4 + r;
            if (gr >= M) continue;
            float ri = rinv[wv * 16 + lq * 4 + r];
#pragma unroll
            for (int tb = 0; tb < 8; ++tb) {
                int col = tb * 16 + lm;
                float o = resid[(size_t)gr * 128 + col] + fmaxf(acc[tb][r], 0.f) * ri;
                C[(size_t)gr * ldc + col]  = o;
                Cbf[(size_t)gr * 128 + col] = f2bf(o);
            }
        }
    } else {
#pragma unroll
        for (int r = 0; r < 4; ++r) {
            int gr = m0 + wv * 16 + lq * 4 + r;
            if (gr >= M) continue;
#pragma unroll
            for (int tb = 0; tb < 8; ++tb) {
                int col = tb * 16 + lm;
                Cbf[(size_t)gr * ldc + col] = f2bf(acc[tb][r] + bs[col]);
            }
        }
    }
}

// ---------------------------------------------------------------------------
// CSR construction
// ---------------------------------------------------------------------------
__global__ void deg_k(const int* __restrict__ dst, int* __restrict__ deg) {
    int e = blockIdx.x * 256 + threadIdx.x;
    if (e < NE) atomicAdd(&deg[dst[e]], 1);
}

__global__ void scan1_k(const int* __restrict__ deg, int* __restrict__ rp,
                        int* __restrict__ bsum) {
    __shared__ int sh[512];
    int tid = threadIdx.x;
    int i = blockIdx.x * 512 + tid;
    int v = (i < NN) ? deg[i] : 0;
    sh[tid] = v;
    __syncthreads();
    for (int ofs = 1; ofs < 512; ofs <<= 1) {
        int x = (tid >= ofs) ? sh[tid - ofs] : 0;
        __syncthreads();
        sh[tid] += x;
        __syncthreads();
    }
    if (i < NN) rp[i] = sh[tid] - v;
    if (tid == 511) bsum[blockIdx.x] = sh[511];
}

__global__ void scan2_k(int* __restrict__ bsum, int nb) {
    __shared__ int sh[128];
    int tid = threadIdx.x;
    int v = (tid < nb) ? bsum[tid] : 0;
    sh[tid] = v;
    __syncthreads();
    for (int ofs = 1; ofs < 128; ofs <<= 1) {
        int x = (tid >= ofs) ? sh[tid - ofs] : 0;
        __syncthreads();
        sh[tid] += x;
        __syncthreads();
    }
    if (tid < nb) bsum[tid] = sh[tid] - v;
}

__global__ void scan3_k(int* __restrict__ rp, const int* __restrict__ bsum,
                        const int* __restrict__ deg, float* __restrict__ invd) {
    int i = blockIdx.x * 512 + threadIdx.x;
    if (i < NN) {
        rp[i] += bsum[blockIdx.x];
        int d = deg[i];
        invd[i] = 1.0f / (float)(d > 1 ? d : 1);
    }
    if (i == NN) rp[NN] = NE;
}

__global__ void fill_k(const int* __restrict__ src, const int* __restrict__ dst,
                       const int* __restrict__ rp, int* __restrict__ cnt,
                       int* __restrict__ srt) {
    int e = blockIdx.x * 256 + threadIdx.x;
    if (e < NE) {
        int d = dst[e];
        int pos = atomicAdd(&cnt[d], 1);
        srt[rp[d] + pos] = src[e];
    }
}

// ---------------------------------------------------------------------------
// Mean aggregation, one WAVE per node, bf16 in, bf16 out, fp32 accumulate.
// ---------------------------------------------------------------------------
__launch_bounds__(256, 8)
__global__ void agg_k(const unsigned short* __restrict__ hbf,
                      const int* __restrict__ rp, const int* __restrict__ srt,
                      const float* __restrict__ invd,
                      unsigned short* __restrict__ cbf) {
    int gw   = (blockIdx.x * 256 + threadIdx.x) >> 6;
    int lane = threadIdx.x & 63;
    if (gw >= NN) return;
    int b = rp[gw], e = rp[gw + 1];
    float a0 = 0.f, a1 = 0.f;
    int j = b;
    for (; j + 4 <= e; j += 4) {
        int s0 = srt[j], s1 = srt[j + 1], s2 = srt[j + 2], s3 = srt[j + 3];
        unsigned u0 = *(const unsigned*)&hbf[(size_t)s0 * 128 + lane * 2];
        unsigned u1 = *(const unsigned*)&hbf[(size_t)s1 * 128 + lane * 2];
        unsigned u2 = *(const unsigned*)&hbf[(size_t)s2 * 128 + lane * 2];
        unsigned u3 = *(const unsigned*)&hbf[(size_t)s3 * 128 + lane * 2];
        a0 += bflo(u0) + bflo(u1) + bflo(u2) + bflo(u3);
        a1 += bfhi(u0) + bfhi(u1) + bfhi(u2) + bfhi(u3);
    }
    for (; j < e; ++j) {
        unsigned u = *(const unsigned*)&hbf[(size_t)srt[j] * 128 + lane * 2];
        a0 += bflo(u); a1 += bfhi(u);
    }
    float iv = invd[gw];
    *(unsigned*)&cbf[(size_t)gw * 128 + lane * 2] = packbf(a0 * iv, a1 * iv);
}

// ---------------------------------------------------------------------------
// Prep (single launch): Wct[4][128n][256k] = bf16(Wconv^T per layer);
// Wefft[256n][128k] = bf16 p/q-factored MLP0 weight; beff; W1tg[64n][128k].
// ---------------------------------------------------------------------------
__global__ void prep_k(const float* __restrict__ Wconv, const float* __restrict__ W0,
                       const float* __restrict__ b0, const float* __restrict__ W1,
                       unsigned short* __restrict__ Wct,
                       unsigned short* __restrict__ Wefft,
                       float* __restrict__ beff, unsigned short* __restrict__ W1tg) {
    int i = blockIdx.x * 256 + threadIdx.x;
    if (i < 131072) {
        int lyr = i >> 15, r = i & 32767, n = r >> 8, k = r & 255;
        Wct[i] = f2bf(Wconv[(size_t)lyr * 32768 + k * 128 + n]);
    } else if (i < 131072 + 32768) {
        int j = i - 131072, n = j >> 7, k = j & 127;
        float v = (n < 128) ? W0[k * 128 + n] : W0[(128 + k) * 128 + (n - 128)];
        Wefft[j] = f2bf(v);
    } else if (i < 131072 + 32768 + 8192) {
        int j = i - 131072 - 32768, n = j >> 7, k = j & 127;
        W1tg[j] = f2bf(W1[k * 64 + n]);
    } else if (i < 131072 + 32768 + 8192 + 256) {
        int j = i - 131072 - 32768 - 8192;
        beff[j] = (j < 128) ? b0[j] : 0.f;
    }
}

// ---------------------------------------------------------------------------
// Fused edge readout (MFMA): e0 = relu(p[src]+q[dst]) bf16; e1 = relu(e0@W1+b1)
// via mfma_f32_16x16x32_bf16; out = e1@W2+b2. 64 edges/block.
// ---------------------------------------------------------------------------
__launch_bounds__(256, 4)
__global__ void edge_mlp_k(const unsigned short* __restrict__ pq,
                           const int* __restrict__ esrc, const int* __restrict__ edst,
                           const unsigned short* __restrict__ W1tg,
                           const float* __restrict__ b1,
                           const float* __restrict__ W2, const float* __restrict__ b2,
                           float* __restrict__ out)
{
    __shared__ __align__(16) unsigned short E0s[64][136];
    __shared__ __align__(16) unsigned short W1s[64][136];
    __shared__ float b1s[64];
    __shared__ float W2s[128];
    __shared__ int ss[64], dd[64];
    const int t = threadIdx.x;
    const int e0 = blockIdx.x * 64;

#pragma unroll
    for (int p = 0; p < 4; ++p) {
        int idx = t * 32 + p * 8;
        int n = idx >> 7, col = idx & 127;
        *(uint4*)&W1s[n][col] = *(const uint4*)&W1tg[idx];
    }
    if (t < 64)  b1s[t] = b1[t];
    if (t < 128) W2s[t] = W2[t];
    if (t < 64) { ss[t] = esrc[e0 + t]; dd[t] = edst[e0 + t]; }
    __syncthreads();

    {
        const int ei = t >> 2;
        const int fs = (t & 3) * 32;
        const unsigned short* pr = pq + (size_t)ss[ei] * 256 + fs;
        const unsigned short* qr = pq + (size_t)dd[ei] * 256 + 128 + fs;
#pragma unroll
        for (int j = 0; j < 4; ++j) {
            uint4 a = *(const uint4*)(pr + j * 8);
            uint4 b = *(const uint4*)(qr + j * 8);
            uint4 r;
            r.x = packbf(fmaxf(bflo(a.x) + bflo(b.x), 0.f),
                         fmaxf(bfhi(a.x) + bfhi(b.x), 0.f));
            r.y = packbf(fmaxf(bflo(a.y) + bflo(b.y), 0.f),
                         fmaxf(bfhi(a.y) + bfhi(b.y), 0.f));
            r.z = packbf(fmaxf(bflo(a.z) + bflo(b.z), 0.f),
                         fmaxf(bfhi(a.z) + bfhi(b.z), 0.f));
            r.w = packbf(fmaxf(bflo(a.w) + bflo(b.w), 0.f),
                         fmaxf(bfhi(a.w) + bfhi(b.w), 0.f));
            *(uint4*)&E0s[ei][fs + j * 8] = r;
        }
    }
    __syncthreads();

    const int wv = t >> 6;
    const int l  = t & 63;
    const int lq = l >> 4, lm = l & 15;
    frag_cd acc[4];
#pragma unroll
    for (int tb = 0; tb < 4; ++tb) acc[tb] = (frag_cd){0.f, 0.f, 0.f, 0.f};
    const int erow = wv * 16 + lm;
#pragma unroll
    for (int kb = 0; kb < 4; ++kb) {
        frag_ab af = *(const frag_ab*)&E0s[erow][kb * 32 + lq * 8];
#pragma unroll
        for (int tb = 0; tb < 4; ++tb) {
            frag_ab bf = *(const frag_ab*)&W1s[tb * 16 + lm][kb * 32 + lq * 8];
            acc[tb] = __builtin_amdgcn_mfma_f32_16x16x32_bf16(af, bf, acc[tb], 0, 0, 0);
        }
    }
    __syncthreads();

    float* e1t = (float*)&W1s[0][0];            // [64][68] fp32 overlay
#pragma unroll
    for (int tb = 0; tb < 4; ++tb) {
        int o = tb * 16 + lm;
        float bias = b1s[o];
#pragma unroll
        for (int r = 0; r < 4; ++r) {
            int e = wv * 16 + lq * 4 + r;
            e1t[(size_t)o * 68 + e] = fmaxf(acc[tb][r] + bias, 0.f);
        }
    }
    __syncthreads();

    if (t < 128) {
        int e = t >> 1, cc = t & 1;
        float s = b2[cc];
#pragma unroll 8
        for (int o = 0; o < 64; ++o) s += e1t[(size_t)o * 68 + e] * W2s[o * 2 + cc];
        out[(size_t)(e0 + e) * 2 + cc] = s;
    }
}

// ---------------------------------------------------------------------------
extern "C" void kernel_launch(void* const* d_in, const int* in_sizes, int n_in,
                              void* d_out, int out_size, void* d_ws, size_t ws_size,
                              hipStream_t stream)
{
    const float* x    = (const float*)d_in[0];
    const int*   esrc = (const int*)  d_in[1];
    const int*   edst = (const int*)  d_in[2];
    const float* Wemb  = (const float*)d_in[5];
    const float* bemb  = (const float*)d_in[6];
    const float* Wconv = (const float*)d_in[7];
    const float* bconv = (const float*)d_in[8];
    const float* Wm0   = (const float*)d_in[9];
    const float* bm0   = (const float*)d_in[10];
    const float* Wm1   = (const float*)d_in[11];
    const float* bm1   = (const float*)d_in[12];
    const float* Wm2   = (const float*)d_in[13];
    const float* bm2   = (const float*)d_in[14];
    float* out = (float*)d_out;

    char* ws = (char*)d_ws;
    size_t off = 0;
    auto alloc = [&](size_t bytes) -> void* {
        void* p = ws + off;
        off = (off + bytes + 255) & ~(size_t)255;
        return p;
    };
    float*          h0   = (float*)alloc((size_t)NN * 128 * 4);
    float*          h1   = (float*)alloc((size_t)NN * 128 * 4);   // pq overlays
    unsigned short* h0bf = (unsigned short*)alloc((size_t)NN * 128 * 2);
    unsigned short* h1bf = (unsigned short*)alloc((size_t)NN * 128 * 2);
    unsigned short* cbf  = (unsigned short*)alloc((size_t)NN * 128 * 2);
    unsigned short* pqb  = (unsigned short*)h1;                   // [NN][256] bf16
    unsigned short* Wct   = (unsigned short*)alloc(4 * 128 * 256 * 2);
    unsigned short* Wefft = (unsigned short*)alloc(256 * 128 * 2);
    float*          beff  = (float*)alloc(256 * 4);
    unsigned short* W1tg  = (unsigned short*)alloc(64 * 128 * 2);
    int*   deg  = (int*)alloc((size_t)NN * 4);
    int*   rp   = (int*)alloc((size_t)(NN + 1) * 4);
    int*   cnt  = (int*)alloc((size_t)NN * 4);
    float* invd = (float*)alloc((size_t)NN * 4);
    int*   bsum = (int*)alloc(512);
    int*   srt  = (int*)alloc((size_t)NE * 4);
    (void)ws_size; (void)in_sizes; (void)n_in; (void)out_size;

    hipMemsetAsync(deg, 0, (size_t)NN * 4, stream);
    hipMemsetAsync(cnt, 0, (size_t)NN * 4, stream);

    // h0 = x @ Wemb + bemb  (fp32 + bf16 mirror)
    gemm_k<64, 4><<<dim3((NN + 63) / 64), 256, 0, stream>>>(
        x, 64, Wemb, 128, bemb, h0, h0bf, 128, NN, 64);

    // CSR build
    deg_k  <<<(NE + 255) / 256, 256, 0, stream>>>(edst, deg);
    scan1_k<<<(NN + 511) / 512, 512, 0, stream>>>(deg, rp, bsum);
    scan2_k<<<1, 128, 0, stream>>>(bsum, (NN + 511) / 512);
    scan3_k<<<(NN + 511) / 512, 512, 0, stream>>>(rp, bsum, deg, invd);
    fill_k <<<(NE + 255) / 256, 256, 0, stream>>>(esrc, edst, rp, cnt, srt);

    // weight prep (bf16 transposes)
    prep_k<<<(131072 + 32768 + 8192 + 256 + 255) / 256, 256, 0, stream>>>(
        Wconv, Wm0, bm0, Wm1, Wct, Wefft, beff, W1tg);

    // 4 SAGE layers (MFMA)
    float* hc = h0; float* hn = h1;
    unsigned short* hcbf = h0bf; unsigned short* hnbf = h1bf;
    for (int l = 0; l < 4; ++l) {
        agg_k<<<(NN + 3) / 4, 256, 0, stream>>>(hcbf, rp, srt, invd, cbf);
        mfma_gemm_k<EPI_LAYER><<<dim3((NN + 63) / 64, 1), 256, 0, stream>>>(
            hcbf, cbf, 128, 128, Wct + (size_t)l * 128 * 256,
            bconv + (size_t)l * 128, hn, hnbf, 128, hc, NN, 256);
        float* tf = hc; hc = hn; hn = tf;
        unsigned short* tb = hcbf; hcbf = hnbf; hnbf = tb;
    }
    // after 4 layers: hc == h0, hcbf == h0bf; h1 (and h1bf) dead -> pq reuses h1

    // pq = bf16(h @ Weff + beff)  [NN][256]
    mfma_gemm_k<EPI_PQBF><<<dim3((NN + 63) / 64, 2), 256, 0, stream>>>(
        hcbf, nullptr, 128, 1 << 30, Wefft, beff, nullptr, pqb, 256, nullptr, NN, 128);

    // fused edge readout
    edge_mlp_k<<<NE / 64, 256, 0, stream>>>(pqb, esrc, edst, W1tg, bm1, Wm2, bm2, out);
}

// Round 4
// 514.332 us; speedup vs baseline: 2.0801x; 1.0383x over previous
//
#include <hip/hip_runtime.h>

constexpr int NN  = 50000;   // nodes
constexpr int NE  = 800000;  // edges

using frag_ab = __attribute__((ext_vector_type(8))) short;  // 8 bf16
using frag_cd = __attribute__((ext_vector_type(4))) float;  // 4 fp32

__device__ __forceinline__ unsigned short f2bf(float f) {   // RNE
    union { float f; unsigned u; } v; v.f = f;
    unsigned r = v.u + 0x7FFFu + ((v.u >> 16) & 1u);
    return (unsigned short)(r >> 16);
}
__device__ __forceinline__ float bflo(unsigned u) {
    union { unsigned u; float f; } v; v.u = u << 16; return v.f;
}
__device__ __forceinline__ float bfhi(unsigned u) {
    union { unsigned u; float f; } v; v.u = u & 0xFFFF0000u; return v.f;
}
__device__ __forceinline__ float bfs(unsigned short u) {
    union { unsigned u; float f; } v; v.u = (unsigned)u << 16; return v.f;
}
__device__ __forceinline__ unsigned packbf(float a, float b) {       // RNE
    return (unsigned)f2bf(a) | ((unsigned)f2bf(b) << 16);
}
__device__ __forceinline__ unsigned packbf_fast(float a, float b) {  // round-half-up
    union { float f; unsigned u; } ua, ub; ua.f = a; ub.f = b;
    return ((ua.u + 0x8000u) >> 16) | ((ub.u + 0x8000u) & 0xFFFF0000u);
}

enum { EPI_LAYER = 1, EPI_PQBF = 2 };

// ---------------------------------------------------------------------------
// fp32 register-tiled GEMM — embed layer only (K=64, fp32 x). bf16 out only.
// ---------------------------------------------------------------------------
template<int BM, int TM>
__launch_bounds__(256, 2)
__global__ void gemm_k(const float* __restrict__ A0, int lda,
                       const float* __restrict__ W, int ldw,
                       const float* __restrict__ bias,
                       unsigned short* __restrict__ Cbf, int M, int K)
{
    static_assert(BM == TM * 16, "bad tile");
    constexpr int BK = 64;
    constexpr int TN = 8;
    __shared__ float As[BK][BM + 4];
    __shared__ float Ws[BK][128];

    const int t  = threadIdx.x;
    const int tm = t >> 4;
    const int tn = t & 15;
    const int m0 = blockIdx.x * BM;

    float acc[TM][TN];
#pragma unroll
    for (int i = 0; i < TM; ++i)
#pragma unroll
        for (int j = 0; j < TN; ++j) acc[i][j] = 0.f;

    for (int kt = 0; kt < K; kt += BK) {
#pragma unroll
        for (int p = 0; p < BM / 16; ++p) {
            int rl = p * 16 + (t >> 4);
            int gm = m0 + rl;
            int kk = (t & 15) * 4;
            float4 v = make_float4(0.f, 0.f, 0.f, 0.f);
            if (gm < M) v = *(const float4*)&A0[(size_t)gm * lda + kt + kk];
            As[kk + 0][rl] = v.x; As[kk + 1][rl] = v.y;
            As[kk + 2][rl] = v.z; As[kk + 3][rl] = v.w;
        }
#pragma unroll
        for (int p = 0; p < 8; ++p) {
            int kr = p * 8 + (t >> 5);
            int nc = (t & 31) * 4;
            *(float4*)&Ws[kr][nc] = *(const float4*)&W[(size_t)(kt + kr) * ldw + nc];
        }
        __syncthreads();
#pragma unroll 8
        for (int k = 0; k < BK; ++k) {
            float a[TM], wv[TN];
            float4 x0 = *(const float4*)&As[k][tm * TM];
            a[0]=x0.x; a[1]=x0.y; a[2]=x0.z; a[3]=x0.w;
            float4 w0 = *(const float4*)&Ws[k][tn * 8];
            float4 w1 = *(const float4*)&Ws[k][tn * 8 + 4];
            wv[0]=w0.x; wv[1]=w0.y; wv[2]=w0.z; wv[3]=w0.w;
            wv[4]=w1.x; wv[5]=w1.y; wv[6]=w1.z; wv[7]=w1.w;
#pragma unroll
            for (int i = 0; i < TM; ++i)
#pragma unroll
                for (int j = 0; j < TN; ++j) acc[i][j] += a[i] * wv[j];
        }
        __syncthreads();
    }

    float4 bv0 = *(const float4*)&bias[tn * 8];
    float4 bv1 = *(const float4*)&bias[tn * 8 + 4];
    float bb[8] = {bv0.x, bv0.y, bv0.z, bv0.w, bv1.x, bv1.y, bv1.z, bv1.w};

#pragma unroll
    for (int i = 0; i < TM; ++i) {
        int gm = m0 + tm * TM + i;
        if (gm >= M) continue;
        float o[8];
#pragma unroll
        for (int j = 0; j < 8; ++j) o[j] = acc[i][j] + bb[j];
        uint4 mv = make_uint4(packbf(o[0], o[1]), packbf(o[2], o[3]),
                              packbf(o[4], o[5]), packbf(o[6], o[7]));
        *(uint4*)&Cbf[(size_t)gm * 128 + tn * 8] = mv;
    }
}

// ---------------------------------------------------------------------------
// MFMA bf16 GEMM. Block: 64 rows x 128 cols, 4 waves, BK=64.
// EPI_LAYER: bundle = acc+bias; out = bf16(resid_bf + relu(bundle)/max(||.||,eps))
// EPI_PQBF : out = bf16(acc + bias), col offset by*128, row stride ldc.
// ---------------------------------------------------------------------------
template<int EPI>
__launch_bounds__(256, 4)
__global__ void mfma_gemm_k(const unsigned short* __restrict__ A0,
                            const unsigned short* __restrict__ A1,
                            int lda, int kSplit,
                            const unsigned short* __restrict__ Wt,
                            const float* __restrict__ bias,
                            unsigned short* __restrict__ Cbf, int ldc,
                            const unsigned short* __restrict__ residbf,
                            int M, int K)
{
    __shared__ __align__(16) unsigned short As[64][72];    // [row][k], pad 8
    __shared__ __align__(16) unsigned short Ws[128][72];   // [n][k],  pad 8
    __shared__ float bs[128];
    __shared__ float part[(EPI == EPI_LAYER) ? 64 : 1][17];
    __shared__ float rinv[(EPI == EPI_LAYER) ? 64 : 1];

    const int t  = threadIdx.x;
    const int by = blockIdx.y;
    Wt   += (size_t)by * 128 * K;
    bias += (size_t)by * 128;
    if constexpr (EPI == EPI_PQBF) Cbf += (size_t)by * 128;
    const int m0 = blockIdx.x * 64;

    if (t < 128) bs[t] = bias[t];

    const int wv = t >> 6, l = t & 63, lq = l >> 4, lm = l & 15;
    frag_cd acc[8];
#pragma unroll
    for (int tb = 0; tb < 8; ++tb) acc[tb] = (frag_cd){0.f, 0.f, 0.f, 0.f};

    for (int kt = 0; kt < K; kt += 64) {
        const unsigned short* Asrc = (kt < kSplit) ? A0 : A1;
        const int kcol = (kt < kSplit) ? kt : kt - kSplit;
#pragma unroll
        for (int p = 0; p < 2; ++p) {
            int idx = p * 256 + t;            // 512 uint4 = 64 x 64 bf16
            int row = idx >> 3, c4 = idx & 7;
            int gm = m0 + row;
            uint4 v = make_uint4(0, 0, 0, 0);
            if (gm < M) v = *(const uint4*)&Asrc[(size_t)gm * lda + kcol + c4 * 8];
            *(uint4*)&As[row][c4 * 8] = v;
        }
#pragma unroll
        for (int p = 0; p < 4; ++p) {
            int idx = p * 256 + t;            // 1024 uint4 = 128 x 64 bf16
            int n = idx >> 3, c4 = idx & 7;
            *(uint4*)&Ws[n][c4 * 8] = *(const uint4*)&Wt[(size_t)n * K + kt + c4 * 8];
        }
        __syncthreads();
#pragma unroll
        for (int kb = 0; kb < 2; ++kb) {
            frag_ab af = *(const frag_ab*)&As[wv * 16 + lm][kb * 32 + lq * 8];
#pragma unroll
            for (int tb = 0; tb < 8; ++tb) {
                frag_ab bf = *(const frag_ab*)&Ws[tb * 16 + lm][kb * 32 + lq * 8];
                acc[tb] = __builtin_amdgcn_mfma_f32_16x16x32_bf16(af, bf, acc[tb], 0, 0, 0);
            }
        }
        __syncthreads();
    }

    if constexpr (EPI == EPI_LAYER) {
        float sq[4] = {0.f, 0.f, 0.f, 0.f};
#pragma unroll
        for (int tb = 0; tb < 8; ++tb) {
            float b = bs[tb * 16 + lm];
#pragma unroll
            for (int r = 0; r < 4; ++r) {
                acc[tb][r] += b;
                sq[r] += acc[tb][r] * acc[tb][r];
            }
        }
#pragma unroll
        for (int r = 0; r < 4; ++r) part[wv * 16 + lq * 4 + r][lm] = sq[r];
        __syncthreads();
        if (t < 64) {
            float s = 0.f;
#pragma unroll
            for (int c = 0; c < 16; ++c) s += part[t][c];
            rinv[t] = 1.0f / fmaxf(sqrtf(s), 1e-12f);
        }
        __syncthreads();
#pragma unroll
        for (int r = 0; r < 4; ++r) {
            int gr = m0 + wv * 16 + lq * 4 + r;
            if (gr >= M) continue;
            float ri = rinv[wv * 16 + lq * 4 + r];
#pragma unroll
            for (int tb = 0; tb < 8; ++tb) {
                int col = tb * 16 + lm;
                float o = bfs(residbf[(size_t)gr * 128 + col]) +
                          fmaxf(acc[tb][r], 0.f) * ri;
                Cbf[(size_t)gr * 128 + col] = f2bf(o);
            }
        }
    } else {
#pragma unroll
        for (int r = 0; r < 4; ++r) {
            int gr = m0 + wv * 16 + lq * 4 + r;
            if (gr >= M) continue;
#pragma unroll
            for (int tb = 0; tb < 8; ++tb) {
                int col = tb * 16 + lm;
                Cbf[(size_t)gr * ldc + col] = f2bf(acc[tb][r] + bs[col]);
            }
        }
    }
}

// ---------------------------------------------------------------------------
// CSR construction (also records per-position dst node and original edge id)
// ---------------------------------------------------------------------------
__global__ void deg_k(const int* __restrict__ dst, int* __restrict__ deg) {
    int e = blockIdx.x * 256 + threadIdx.x;
    if (e < NE) atomicAdd(&deg[dst[e]], 1);
}

__global__ void scan1_k(const int* __restrict__ deg, int* __restrict__ rp,
                        int* __restrict__ bsum) {
    __shared__ int sh[512];
    int tid = threadIdx.x;
    int i = blockIdx.x * 512 + tid;
    int v = (i < NN) ? deg[i] : 0;
    sh[tid] = v;
    __syncthreads();
    for (int ofs = 1; ofs < 512; ofs <<= 1) {
        int x = (tid >= ofs) ? sh[tid - ofs] : 0;
        __syncthreads();
        sh[tid] += x;
        __syncthreads();
    }
    if (i < NN) rp[i] = sh[tid] - v;
    if (tid == 511) bsum[blockIdx.x] = sh[511];
}

__global__ void scan2_k(int* __restrict__ bsum, int nb) {
    __shared__ int sh[128];
    int tid = threadIdx.x;
    int v = (tid < nb) ? bsum[tid] : 0;
    sh[tid] = v;
    __syncthreads();
    for (int ofs = 1; ofs < 128; ofs <<= 1) {
        int x = (tid >= ofs) ? sh[tid - ofs] : 0;
        __syncthreads();
        sh[tid] += x;
        __syncthreads();
    }
    if (tid < nb) bsum[tid] = sh[tid] - v;
}

__global__ void scan3_k(int* __restrict__ rp, const int* __restrict__ bsum,
                        const int* __restrict__ deg, float* __restrict__ invd) {
    int i = blockIdx.x * 512 + threadIdx.x;
    if (i < NN) {
        rp[i] += bsum[blockIdx.x];
        int d = deg[i];
        invd[i] = 1.0f / (float)(d > 1 ? d : 1);
    }
    if (i == NN) rp[NN] = NE;
}

__global__ void fill_k(const int* __restrict__ src, const int* __restrict__ dst,
                       const int* __restrict__ rp, int* __restrict__ cnt,
                       int* __restrict__ srt, int* __restrict__ dste,
                       int* __restrict__ eide) {
    int e = blockIdx.x * 256 + threadIdx.x;
    if (e < NE) {
        int d = dst[e];
        int pos = rp[d] + atomicAdd(&cnt[d], 1);
        srt[pos]  = src[e];
        dste[pos] = d;
        eide[pos] = e;
    }
}

// ---------------------------------------------------------------------------
// Mean aggregation, one WAVE per node, bf16 in/out, fp32 accumulate.
// ---------------------------------------------------------------------------
__launch_bounds__(256, 8)
__global__ void agg_k(const unsigned short* __restrict__ hbf,
                      const int* __restrict__ rp, const int* __restrict__ srt,
                      const float* __restrict__ invd,
                      unsigned short* __restrict__ cbf) {
    int gw   = (blockIdx.x * 256 + threadIdx.x) >> 6;
    int lane = threadIdx.x & 63;
    if (gw >= NN) return;
    int b = rp[gw], e = rp[gw + 1];
    float a0 = 0.f, a1 = 0.f;
    int j = b;
    for (; j + 4 <= e; j += 4) {
        int s0 = srt[j], s1 = srt[j + 1], s2 = srt[j + 2], s3 = srt[j + 3];
        unsigned u0 = *(const unsigned*)&hbf[(size_t)s0 * 128 + lane * 2];
        unsigned u1 = *(const unsigned*)&hbf[(size_t)s1 * 128 + lane * 2];
        unsigned u2 = *(const unsigned*)&hbf[(size_t)s2 * 128 + lane * 2];
        unsigned u3 = *(const unsigned*)&hbf[(size_t)s3 * 128 + lane * 2];
        a0 += bflo(u0) + bflo(u1) + bflo(u2) + bflo(u3);
        a1 += bfhi(u0) + bfhi(u1) + bfhi(u2) + bfhi(u3);
    }
    for (; j < e; ++j) {
        unsigned u = *(const unsigned*)&hbf[(size_t)srt[j] * 128 + lane * 2];
        a0 += bflo(u); a1 += bfhi(u);
    }
    float iv = invd[gw];
    *(unsigned*)&cbf[(size_t)gw * 128 + lane * 2] = packbf(a0 * iv, a1 * iv);
}

// ---------------------------------------------------------------------------
// Prep: Wct[4][128n][256k]; Wefft[256n][128k] (p/q factored MLP0); beff; W1tg.
// ---------------------------------------------------------------------------
__global__ void prep_k(const float* __restrict__ Wconv, const float* __restrict__ W0,
                       const float* __restrict__ b0, const float* __restrict__ W1,
                       unsigned short* __restrict__ Wct,
                       unsigned short* __restrict__ Wefft,
                       float* __restrict__ beff, unsigned short* __restrict__ W1tg) {
    int i = blockIdx.x * 256 + threadIdx.x;
    if (i < 131072) {
        int lyr = i >> 15, r = i & 32767, n = r >> 8, k = r & 255;
        Wct[i] = f2bf(Wconv[(size_t)lyr * 32768 + k * 128 + n]);
    } else if (i < 131072 + 32768) {
        int j = i - 131072, n = j >> 7, k = j & 127;
        float v = (n < 128) ? W0[k * 128 + n] : W0[(128 + k) * 128 + (n - 128)];
        Wefft[j] = f2bf(v);
    } else if (i < 131072 + 32768 + 8192) {
        int j = i - 131072 - 32768, n = j >> 7, k = j & 127;
        W1tg[j] = f2bf(W1[k * 64 + n]);
    } else if (i < 131072 + 32768 + 8192 + 256) {
        int j = i - 131072 - 32768 - 8192;
        beff[j] = (j < 128) ? b0[j] : 0.f;
    }
}

// ---------------------------------------------------------------------------
// Fused edge readout (MFMA), CSR edge order: block handles 64 consecutive CSR
// positions (dst-sorted -> q[dst] rows are L1-local). Output scattered by
// original edge id. e1t layout [edge][69] (stride 69, gcd(69,32)=1 -> no
// multi-way LDS bank conflicts).
// ---------------------------------------------------------------------------
__launch_bounds__(256, 4)
__global__ void edge_mlp_k(const unsigned short* __restrict__ pq,
                           const int* __restrict__ srt,  const int* __restrict__ dste,
                           const int* __restrict__ eide,
                           const unsigned short* __restrict__ W1tg,
                           const float* __restrict__ b1,
                           const float* __restrict__ W2, const float* __restrict__ b2,
                           float* __restrict__ out)
{
    __shared__ __align__(16) unsigned char pool[34816 + 2848];
    unsigned short* E0s = (unsigned short*)pool;             // [64][136]
    unsigned short* W1s = (unsigned short*)(pool + 17408);   // [64][136]
    float* e1t = (float*)pool;                               // [64][69] overlay
    float* b1s = (float*)(pool + 34816);                     // [64]
    float* W2s = b1s + 64;                                   // [128]
    int*   ss  = (int*)(W2s + 128);                          // [64]
    int*   dd  = ss + 64;                                    // [64]
    int*   ee  = dd + 64;                                    // [64]

    const int t = threadIdx.x;
    const int p0 = blockIdx.x * 64;

#pragma unroll
    for (int p = 0; p < 4; ++p) {
        int idx = t * 32 + p * 8;                 // 8192 ushorts of W1t
        int n = idx >> 7, col = idx & 127;
        *(uint4*)&W1s[n * 136 + col] = *(const uint4*)&W1tg[idx];
    }
    if (t < 64)  b1s[t] = b1[t];
    if (t < 128) W2s[t] = W2[t];
    if (t < 64) { ss[t] = srt[p0 + t]; dd[t] = dste[p0 + t]; ee[t] = eide[p0 + t]; }
    __syncthreads();

    // phase 1: e0 = relu(p[src] + q[dst]) -> E0s bf16 (fast pack)
    {
        const int ei = t >> 2;
        const int fs = (t & 3) * 32;
        const unsigned short* pr = pq + (size_t)ss[ei] * 256 + fs;
        const unsigned short* qr = pq + (size_t)dd[ei] * 256 + 128 + fs;
#pragma unroll
        for (int j = 0; j < 4; ++j) {
            uint4 a = *(const uint4*)(pr + j * 8);
            uint4 b = *(const uint4*)(qr + j * 8);
            uint4 r;
            r.x = packbf_fast(fmaxf(bflo(a.x) + bflo(b.x), 0.f),
                              fmaxf(bfhi(a.x) + bfhi(b.x), 0.f));
            r.y = packbf_fast(fmaxf(bflo(a.y) + bflo(b.y), 0.f),
                              fmaxf(bfhi(a.y) + bfhi(b.y), 0.f));
            r.z = packbf_fast(fmaxf(bflo(a.z) + bflo(b.z), 0.f),
                              fmaxf(bfhi(a.z) + bfhi(b.z), 0.f));
            r.w = packbf_fast(fmaxf(bflo(a.w) + bflo(b.w), 0.f),
                              fmaxf(bfhi(a.w) + bfhi(b.w), 0.f));
            *(uint4*)&E0s[ei * 136 + fs + j * 8] = r;
        }
    }
    __syncthreads();

    // phase 2: MLP1 via MFMA (wave = 16 edges x 64 outs)
    const int wv = t >> 6;
    const int l  = t & 63;
    const int lq = l >> 4, lm = l & 15;
    frag_cd acc[4];
#pragma unroll
    for (int tb = 0; tb < 4; ++tb) acc[tb] = (frag_cd){0.f, 0.f, 0.f, 0.f};
    const int erow = wv * 16 + lm;
#pragma unroll
    for (int kb = 0; kb < 4; ++kb) {
        frag_ab af = *(const frag_ab*)&E0s[erow * 136 + kb * 32 + lq * 8];
#pragma unroll
        for (int tb = 0; tb < 4; ++tb) {
            frag_ab bf = *(const frag_ab*)&W1s[(tb * 16 + lm) * 136 + kb * 32 + lq * 8];
            acc[tb] = __builtin_amdgcn_mfma_f32_16x16x32_bf16(af, bf, acc[tb], 0, 0, 0);
        }
    }
    __syncthreads();                 // all E0s/W1s reads done before overlay

    // epilogue: e1[edge][out] = relu(acc + b1)
#pragma unroll
    for (int tb = 0; tb < 4; ++tb) {
        int o = tb * 16 + lm;                   // C/D: col = lane&15
        float bias = b1s[o];
#pragma unroll
        for (int r = 0; r < 4; ++r) {           // row = (lane>>4)*4 + reg
            int e = wv * 16 + lq * 4 + r;
            e1t[(size_t)e * 69 + o] = fmaxf(acc[tb][r] + bias, 0.f);
        }
    }
    __syncthreads();

    // phase 3: MLP2 (64 -> 2), scatter by original edge id
    if (t < 128) {
        int e = t & 63, cc = t >> 6;
        float s = b2[cc];
#pragma unroll 8
        for (int o = 0; o < 64; ++o) s += e1t[(size_t)e * 69 + o] * W2s[o * 2 + cc];
        out[(size_t)ee[e] * 2 + cc] = s;
    }
}

// ---------------------------------------------------------------------------
extern "C" void kernel_launch(void* const* d_in, const int* in_sizes, int n_in,
                              void* d_out, int out_size, void* d_ws, size_t ws_size,
                              hipStream_t stream)
{
    const float* x    = (const float*)d_in[0];
    const int*   esrc = (const int*)  d_in[1];
    const int*   edst = (const int*)  d_in[2];
    const float* Wemb  = (const float*)d_in[5];
    const float* bemb  = (const float*)d_in[6];
    const float* Wconv = (const float*)d_in[7];
    const float* bconv = (const float*)d_in[8];
    const float* Wm0   = (const float*)d_in[9];
    const float* bm0   = (const float*)d_in[10];
    const float* Wm1   = (const float*)d_in[11];
    const float* bm1   = (const float*)d_in[12];
    const float* Wm2   = (const float*)d_in[13];
    const float* bm2   = (const float*)d_in[14];
    float* out = (float*)d_out;

    char* ws = (char*)d_ws;
    size_t off = 0;
    auto alloc = [&](size_t bytes) -> void* {
        void* p = ws + off;
        off = (off + bytes + 255) & ~(size_t)255;
        return p;
    };
    unsigned short* h0bf = (unsigned short*)alloc((size_t)NN * 128 * 2);
    unsigned short* h1bf = (unsigned short*)alloc((size_t)NN * 128 * 2);
    unsigned short* cbf  = (unsigned short*)alloc((size_t)NN * 128 * 2);
    unsigned short* pqb  = (unsigned short*)alloc((size_t)NN * 256 * 2);
    unsigned short* Wct   = (unsigned short*)alloc(4 * 128 * 256 * 2);
    unsigned short* Wefft = (unsigned short*)alloc(256 * 128 * 2);
    float*          beff  = (float*)alloc(256 * 4);
    unsigned short* W1tg  = (unsigned short*)alloc(64 * 128 * 2);
    int*   deg  = (int*)alloc((size_t)NN * 4);
    int*   rp   = (int*)alloc((size_t)(NN + 1) * 4);
    int*   cnt  = (int*)alloc((size_t)NN * 4);
    float* invd = (float*)alloc((size_t)NN * 4);
    int*   bsum = (int*)alloc(512);
    int*   srt  = (int*)alloc((size_t)NE * 4);
    int*   dste = (int*)alloc((size_t)NE * 4);
    int*   eide = (int*)alloc((size_t)NE * 4);
    (void)ws_size; (void)in_sizes; (void)n_in; (void)out_size;

    hipMemsetAsync(deg, 0, (size_t)NN * 4, stream);
    hipMemsetAsync(cnt, 0, (size_t)NN * 4, stream);

    // h0 = bf16(x @ Wemb + bemb)
    gemm_k<64, 4><<<dim3((NN + 63) / 64), 256, 0, stream>>>(
        x, 64, Wemb, 128, bemb, h0bf, NN, 64);

    // CSR build
    deg_k  <<<(NE + 255) / 256, 256, 0, stream>>>(edst, deg);
    scan1_k<<<(NN + 511) / 512, 512, 0, stream>>>(deg, rp, bsum);
    scan2_k<<<1, 128, 0, stream>>>(bsum, (NN + 511) / 512);
    scan3_k<<<(NN + 511) / 512, 512, 0, stream>>>(rp, bsum, deg, invd);
    fill_k <<<(NE + 255) / 256, 256, 0, stream>>>(esrc, edst, rp, cnt, srt, dste, eide);

    // weight prep (bf16 transposes)
    prep_k<<<(131072 + 32768 + 8192 + 256 + 255) / 256, 256, 0, stream>>>(
        Wconv, Wm0, bm0, Wm1, Wct, Wefft, beff, W1tg);

    // 4 SAGE layers (MFMA, bf16 residual)
    unsigned short* hcbf = h0bf; unsigned short* hnbf = h1bf;
    for (int l = 0; l < 4; ++l) {
        agg_k<<<(NN + 3) / 4, 256, 0, stream>>>(hcbf, rp, srt, invd, cbf);
        mfma_gemm_k<EPI_LAYER><<<dim3((NN + 63) / 64, 1), 256, 0, stream>>>(
            hcbf, cbf, 128, 128, Wct + (size_t)l * 128 * 256,
            bconv + (size_t)l * 128, hnbf, 128, hcbf, NN, 256);
        unsigned short* tb = hcbf; hcbf = hnbf; hnbf = tb;
    }
    // after 4 layers: hcbf == h0bf

    // pq = bf16(h @ Weff + beff)  [NN][256]
    mfma_gemm_k<EPI_PQBF><<<dim3((NN + 63) / 64, 2), 256, 0, stream>>>(
        hcbf, nullptr, 128, 1 << 30, Wefft, beff, pqb, 256, nullptr, NN, 128);

    // fused edge readout (CSR order)
    edge_mlp_k<<<NE / 64, 256, 0, stream>>>(pqb, srt, dste, eide,
                                            W1tg, bm1, Wm2, bm2, out);
}

// Round 5
// 514.055 us; speedup vs baseline: 2.0812x; 1.0005x over previous
//
#include <hip/hip_runtime.h>

constexpr int NN  = 50000;   // nodes
constexpr int NE  = 800000;  // edges

using frag_ab = __attribute__((ext_vector_type(8))) short;  // 8 bf16
using frag_cd = __attribute__((ext_vector_type(4))) float;  // 4 fp32

__device__ __forceinline__ unsigned short f2bf(float f) {   // RNE
    union { float f; unsigned u; } v; v.f = f;
    unsigned r = v.u + 0x7FFFu + ((v.u >> 16) & 1u);
    return (unsigned short)(r >> 16);
}
__device__ __forceinline__ float bflo(unsigned u) {
    union { unsigned u; float f; } v; v.u = u << 16; return v.f;
}
__device__ __forceinline__ float bfhi(unsigned u) {
    union { unsigned u; float f; } v; v.u = u & 0xFFFF0000u; return v.f;
}
__device__ __forceinline__ float bfs(unsigned short u) {
    union { unsigned u; float f; } v; v.u = (unsigned)u << 16; return v.f;
}
__device__ __forceinline__ unsigned packbf(float a, float b) {       // RNE
    return (unsigned)f2bf(a) | ((unsigned)f2bf(b) << 16);
}
__device__ __forceinline__ unsigned packbf_fast(float a, float b) {  // round-half-up
    union { float f; unsigned u; } ua, ub; ua.f = a; ub.f = b;
    return ((ua.u + 0x8000u) >> 16) | ((ub.u + 0x8000u) & 0xFFFF0000u);
}

enum { EPI_LAYER = 1, EPI_PQBF = 2 };

// ---------------------------------------------------------------------------
// MFMA bf16 GEMM. Block: 64 rows x 128 cols, 4 waves, BK=64.
// EPI_LAYER: bundle = acc+bias; out = bf16(resid_bf + relu(bundle)/max(||.||,eps))
// EPI_PQBF : out = bf16(acc + bias), col offset by*128, row stride ldc.
// ---------------------------------------------------------------------------
template<int EPI>
__launch_bounds__(256, 4)
__global__ void mfma_gemm_k(const unsigned short* __restrict__ A0,
                            const unsigned short* __restrict__ A1,
                            int lda, int kSplit,
                            const unsigned short* __restrict__ Wt,
                            const float* __restrict__ bias,
                            unsigned short* __restrict__ Cbf, int ldc,
                            const unsigned short* __restrict__ residbf,
                            int M, int K)
{
    __shared__ __align__(16) unsigned short As[64][72];    // [row][k], pad 8
    __shared__ __align__(16) unsigned short Ws[128][72];   // [n][k],  pad 8
    __shared__ float bs[128];
    __shared__ float part[(EPI == EPI_LAYER) ? 64 : 1][17];
    __shared__ float rinv[(EPI == EPI_LAYER) ? 64 : 1];

    const int t  = threadIdx.x;
    const int by = blockIdx.y;
    Wt   += (size_t)by * 128 * K;
    bias += (size_t)by * 128;
    if constexpr (EPI == EPI_PQBF) Cbf += (size_t)by * 128;
    const int m0 = blockIdx.x * 64;

    if (t < 128) bs[t] = bias[t];

    const int wv = t >> 6, l = t & 63, lq = l >> 4, lm = l & 15;
    frag_cd acc[8];
#pragma unroll
    for (int tb = 0; tb < 8; ++tb) acc[tb] = (frag_cd){0.f, 0.f, 0.f, 0.f};

    for (int kt = 0; kt < K; kt += 64) {
        const unsigned short* Asrc = (kt < kSplit) ? A0 : A1;
        const int kcol = (kt < kSplit) ? kt : kt - kSplit;
#pragma unroll
        for (int p = 0; p < 2; ++p) {
            int idx = p * 256 + t;            // 512 uint4 = 64 x 64 bf16
            int row = idx >> 3, c4 = idx & 7;
            int gm = m0 + row;
            uint4 v = make_uint4(0, 0, 0, 0);
            if (gm < M) v = *(const uint4*)&Asrc[(size_t)gm * lda + kcol + c4 * 8];
            *(uint4*)&As[row][c4 * 8] = v;
        }
#pragma unroll
        for (int p = 0; p < 4; ++p) {
            int idx = p * 256 + t;            // 1024 uint4 = 128 x 64 bf16
            int n = idx >> 3, c4 = idx & 7;
            *(uint4*)&Ws[n][c4 * 8] = *(const uint4*)&Wt[(size_t)n * K + kt + c4 * 8];
        }
        __syncthreads();
#pragma unroll
        for (int kb = 0; kb < 2; ++kb) {
            frag_ab af = *(const frag_ab*)&As[wv * 16 + lm][kb * 32 + lq * 8];
#pragma unroll
            for (int tb = 0; tb < 8; ++tb) {
                frag_ab bf = *(const frag_ab*)&Ws[tb * 16 + lm][kb * 32 + lq * 8];
                acc[tb] = __builtin_amdgcn_mfma_f32_16x16x32_bf16(af, bf, acc[tb], 0, 0, 0);
            }
        }
        __syncthreads();
    }

    if constexpr (EPI == EPI_LAYER) {
        float sq[4] = {0.f, 0.f, 0.f, 0.f};
#pragma unroll
        for (int tb = 0; tb < 8; ++tb) {
            float b = bs[tb * 16 + lm];
#pragma unroll
            for (int r = 0; r < 4; ++r) {
                acc[tb][r] += b;
                sq[r] += acc[tb][r] * acc[tb][r];
            }
        }
#pragma unroll
        for (int r = 0; r < 4; ++r) part[wv * 16 + lq * 4 + r][lm] = sq[r];
        __syncthreads();
        if (t < 64) {
            float s = 0.f;
#pragma unroll
            for (int c = 0; c < 16; ++c) s += part[t][c];
            rinv[t] = 1.0f / fmaxf(sqrtf(s), 1e-12f);
        }
        __syncthreads();
#pragma unroll
        for (int r = 0; r < 4; ++r) {
            int gr = m0 + wv * 16 + lq * 4 + r;
            if (gr >= M) continue;
            float ri = rinv[wv * 16 + lq * 4 + r];
#pragma unroll
            for (int tb = 0; tb < 8; ++tb) {
                int col = tb * 16 + lm;
                float o = bfs(residbf[(size_t)gr * 128 + col]) +
                          fmaxf(acc[tb][r], 0.f) * ri;
                Cbf[(size_t)gr * 128 + col] = f2bf(o);
            }
        }
    } else {
#pragma unroll
        for (int r = 0; r < 4; ++r) {
            int gr = m0 + wv * 16 + lq * 4 + r;
            if (gr >= M) continue;
#pragma unroll
            for (int tb = 0; tb < 8; ++tb) {
                int col = tb * 16 + lm;
                Cbf[(size_t)gr * ldc + col] = f2bf(acc[tb][r] + bs[col]);
            }
        }
    }
}

// ---------------------------------------------------------------------------
// x -> bf16 cast (embed input)
// ---------------------------------------------------------------------------
__global__ void cast_k(const float* __restrict__ x, unsigned short* __restrict__ xbf,
                       int n8) {
    int i = blockIdx.x * 256 + threadIdx.x;
    if (i >= n8) return;
    float4 a = *(const float4*)&x[(size_t)i * 8];
    float4 b = *(const float4*)&x[(size_t)i * 8 + 4];
    uint4 o = make_uint4(packbf(a.x, a.y), packbf(a.z, a.w),
                         packbf(b.x, b.y), packbf(b.z, b.w));
    *(uint4*)&xbf[(size_t)i * 8] = o;
}

// ---------------------------------------------------------------------------
// CSR construction -> packed records pk[pos] = {src, dst, eid, 0}
// ---------------------------------------------------------------------------
__global__ void deg_k(const int* __restrict__ dst, int* __restrict__ deg) {
    int e = blockIdx.x * 256 + threadIdx.x;
    if (e < NE) atomicAdd(&deg[dst[e]], 1);
}

__global__ void scan1_k(const int* __restrict__ deg, int* __restrict__ rp,
                        int* __restrict__ bsum) {
    __shared__ int sh[512];
    int tid = threadIdx.x;
    int i = blockIdx.x * 512 + tid;
    int v = (i < NN) ? deg[i] : 0;
    sh[tid] = v;
    __syncthreads();
    for (int ofs = 1; ofs < 512; ofs <<= 1) {
        int x = (tid >= ofs) ? sh[tid - ofs] : 0;
        __syncthreads();
        sh[tid] += x;
        __syncthreads();
    }
    if (i < NN) rp[i] = sh[tid] - v;
    if (tid == 511) bsum[blockIdx.x] = sh[511];
}

__global__ void scan2_k(int* __restrict__ bsum, int nb) {
    __shared__ int sh[128];
    int tid = threadIdx.x;
    int v = (tid < nb) ? bsum[tid] : 0;
    sh[tid] = v;
    __syncthreads();
    for (int ofs = 1; ofs < 128; ofs <<= 1) {
        int x = (tid >= ofs) ? sh[tid - ofs] : 0;
        __syncthreads();
        sh[tid] += x;
        __syncthreads();
    }
    if (tid < nb) bsum[tid] = sh[tid] - v;
}

__global__ void scan3_k(int* __restrict__ rp, const int* __restrict__ bsum,
                        const int* __restrict__ deg, float* __restrict__ invd) {
    int i = blockIdx.x * 512 + threadIdx.x;
    if (i < NN) {
        rp[i] += bsum[blockIdx.x];
        int d = deg[i];
        invd[i] = 1.0f / (float)(d > 1 ? d : 1);
    }
    if (i == NN) rp[NN] = NE;
}

__global__ void fill_k(const int* __restrict__ src, const int* __restrict__ dst,
                       const int* __restrict__ rp, int* __restrict__ cnt,
                       int4* __restrict__ pk) {
    int e = blockIdx.x * 256 + threadIdx.x;
    if (e < NE) {
        int d = dst[e];
        int pos = rp[d] + atomicAdd(&cnt[d], 1);
        pk[pos] = make_int4(src[e], d, e, 0);
    }
}

// ---------------------------------------------------------------------------
// Mean aggregation, one WAVE per node, bf16 in/out, fp32 accumulate.
// Neighbor list read from packed CSR (field .x = src).
// ---------------------------------------------------------------------------
__launch_bounds__(256, 8)
__global__ void agg_k(const unsigned short* __restrict__ hbf,
                      const int* __restrict__ rp, const int4* __restrict__ pk,
                      const float* __restrict__ invd,
                      unsigned short* __restrict__ cbf) {
    int gw   = (blockIdx.x * 256 + threadIdx.x) >> 6;
    int lane = threadIdx.x & 63;
    if (gw >= NN) return;
    int b = rp[gw], e = rp[gw + 1];
    float a0 = 0.f, a1 = 0.f;
    int j = b;
    for (; j + 4 <= e; j += 4) {
        int s0 = pk[j].x, s1 = pk[j + 1].x, s2 = pk[j + 2].x, s3 = pk[j + 3].x;
        unsigned u0 = *(const unsigned*)&hbf[(size_t)s0 * 128 + lane * 2];
        unsigned u1 = *(const unsigned*)&hbf[(size_t)s1 * 128 + lane * 2];
        unsigned u2 = *(const unsigned*)&hbf[(size_t)s2 * 128 + lane * 2];
        unsigned u3 = *(const unsigned*)&hbf[(size_t)s3 * 128 + lane * 2];
        a0 += bflo(u0) + bflo(u1) + bflo(u2) + bflo(u3);
        a1 += bfhi(u0) + bfhi(u1) + bfhi(u2) + bfhi(u3);
    }
    for (; j < e; ++j) {
        unsigned u = *(const unsigned*)&hbf[(size_t)pk[j].x * 128 + lane * 2];
        a0 += bflo(u); a1 += bfhi(u);
    }
    float iv = invd[gw];
    *(unsigned*)&cbf[(size_t)gw * 128 + lane * 2] = packbf(a0 * iv, a1 * iv);
}

// ---------------------------------------------------------------------------
// Prep: Wct[4][128n][256k]; Wefft[256n][128k] (p/q factored MLP0); W1tg[64n][128k];
// beff; Wembt[128n][64k].
// ---------------------------------------------------------------------------
__global__ void prep_k(const float* __restrict__ Wconv, const float* __restrict__ W0,
                       const float* __restrict__ b0, const float* __restrict__ W1,
                       const float* __restrict__ Wemb,
                       unsigned short* __restrict__ Wct,
                       unsigned short* __restrict__ Wefft,
                       float* __restrict__ beff, unsigned short* __restrict__ W1tg,
                       unsigned short* __restrict__ Wembt) {
    int i = blockIdx.x * 256 + threadIdx.x;
    if (i < 131072) {
        int lyr = i >> 15, r = i & 32767, n = r >> 8, k = r & 255;
        Wct[i] = f2bf(Wconv[(size_t)lyr * 32768 + k * 128 + n]);
    } else if (i < 163840) {
        int j = i - 131072, n = j >> 7, k = j & 127;
        float v = (n < 128) ? W0[k * 128 + n] : W0[(128 + k) * 128 + (n - 128)];
        Wefft[j] = f2bf(v);
    } else if (i < 172032) {
        int j = i - 163840, n = j >> 7, k = j & 127;
        W1tg[j] = f2bf(W1[k * 64 + n]);
    } else if (i < 172288) {
        int j = i - 172032;
        beff[j] = (j < 128) ? b0[j] : 0.f;
    } else if (i < 180480) {
        int j = i - 172288, n = j >> 6, k = j & 63;
        Wembt[j] = f2bf(Wemb[k * 128 + n]);
    }
}

// ---------------------------------------------------------------------------
// Fused edge readout (MFMA), CSR order, 128 edges/block, SINGLE barrier.
// phase 1: e0 = relu(p[src]+q[dst]) -> LDS bf16 (pk read from global)
// phase 2: e1 = relu(e0 @ W1 + b1) via mfma (acc in regs)
// phase 3: out = e1 @ W2 + b2 entirely in-register (shfl_xor reduce over lm),
//          scattered 8-B store by original edge id.
// LDS 53 KB -> 3 blocks/CU.
// ---------------------------------------------------------------------------
__launch_bounds__(256, 3)
__global__ void edge_mlp_k(const unsigned short* __restrict__ pq,
                           const int4* __restrict__ pk,
                           const unsigned short* __restrict__ W1tg,
                           const float* __restrict__ b1,
                           const float* __restrict__ W2, const float* __restrict__ b2,
                           float* __restrict__ out)
{
    __shared__ __align__(16) unsigned short E0s[128][136];  // 34816 B
    __shared__ __align__(16) unsigned short W1s[64][136];   // 17408 B
    __shared__ float b1s[64];
    __shared__ float W2s[128];
    const int t = threadIdx.x;
    const int p0 = blockIdx.x * 128;

    // stage W1 (16 KB), b1, W2
#pragma unroll
    for (int p = 0; p < 4; ++p) {
        int idx = t * 32 + p * 8;               // 8192 ushorts
        *(uint4*)&W1s[idx >> 7][idx & 127] = *(const uint4*)&W1tg[idx];
    }
    if (t < 64)  b1s[t] = b1[t];
    if (t < 128) W2s[t] = W2[t];

    // phase 1: 2 threads/edge, 64 features each
    {
        const int ei = t >> 1;
        const int fs = (t & 1) * 64;
        int4 pkv = pk[p0 + ei];
        const unsigned short* pr = pq + (size_t)pkv.x * 256 + fs;
        const unsigned short* qr = pq + (size_t)pkv.y * 256 + 128 + fs;
#pragma unroll
        for (int j = 0; j < 8; ++j) {
            uint4 a = *(const uint4*)(pr + j * 8);
            uint4 b = *(const uint4*)(qr + j * 8);
            uint4 r;
            r.x = packbf_fast(fmaxf(bflo(a.x) + bflo(b.x), 0.f),
                              fmaxf(bfhi(a.x) + bfhi(b.x), 0.f));
            r.y = packbf_fast(fmaxf(bflo(a.y) + bflo(b.y), 0.f),
                              fmaxf(bfhi(a.y) + bfhi(b.y), 0.f));
            r.z = packbf_fast(fmaxf(bflo(a.z) + bflo(b.z), 0.f),
                              fmaxf(bfhi(a.z) + bfhi(b.z), 0.f));
            r.w = packbf_fast(fmaxf(bflo(a.w) + bflo(b.w), 0.f),
                              fmaxf(bfhi(a.w) + bfhi(b.w), 0.f));
            *(uint4*)&E0s[ei][fs + j * 8] = r;
        }
    }
    __syncthreads();                 // single barrier (covers W1s + E0s)

    // phase 2: MFMA. wave wv: edges [32wv, 32wv+32), 2 row-tiles x 4 out-tiles.
    const int wv = t >> 6, l = t & 63, lq = l >> 4, lm = l & 15;
    frag_cd acc[2][4];
#pragma unroll
    for (int rt = 0; rt < 2; ++rt)
#pragma unroll
        for (int tb = 0; tb < 4; ++tb) acc[rt][tb] = (frag_cd){0.f, 0.f, 0.f, 0.f};
#pragma unroll
    for (int rt = 0; rt < 2; ++rt) {
        const int erow = wv * 32 + rt * 16 + lm;
#pragma unroll
        for (int kb = 0; kb < 4; ++kb) {
            frag_ab af = *(const frag_ab*)&E0s[erow][kb * 32 + lq * 8];
#pragma unroll
            for (int tb = 0; tb < 4; ++tb) {
                frag_ab bf = *(const frag_ab*)&W1s[tb * 16 + lm][kb * 32 + lq * 8];
                acc[rt][tb] = __builtin_amdgcn_mfma_f32_16x16x32_bf16(af, bf, acc[rt][tb], 0, 0, 0);
            }
        }
    }

    // phase 3: in-register MLP2. lane's 4 outs: o = tb*16+lm.
    float b1v[4], w20[4], w21[4];
#pragma unroll
    for (int tb = 0; tb < 4; ++tb) {
        int o = tb * 16 + lm;
        b1v[tb] = b1s[o];
        w20[tb] = W2s[o * 2];
        w21[tb] = W2s[o * 2 + 1];
    }
    const float bo0 = b2[0], bo1 = b2[1];
#pragma unroll
    for (int rt = 0; rt < 2; ++rt) {
#pragma unroll
        for (int r = 0; r < 4; ++r) {
            float s0 = 0.f, s1 = 0.f;
#pragma unroll
            for (int tb = 0; tb < 4; ++tb) {
                float e1 = fmaxf(acc[rt][tb][r] + b1v[tb], 0.f);
                s0 += e1 * w20[tb];
                s1 += e1 * w21[tb];
            }
#pragma unroll
            for (int m = 1; m < 16; m <<= 1) {   // reduce over lm (16 lanes)
                s0 += __shfl_xor(s0, m, 16);
                s1 += __shfl_xor(s1, m, 16);
            }
            if (lm == 0) {
                int e = wv * 32 + rt * 16 + lq * 4 + r;
                int eid = pk[p0 + e].z;
                *(float2*)&out[(size_t)eid * 2] = make_float2(s0 + bo0, s1 + bo1);
            }
        }
    }
}

// ---------------------------------------------------------------------------
extern "C" void kernel_launch(void* const* d_in, const int* in_sizes, int n_in,
                              void* d_out, int out_size, void* d_ws, size_t ws_size,
                              hipStream_t stream)
{
    const float* x    = (const float*)d_in[0];
    const int*   esrc = (const int*)  d_in[1];
    const int*   edst = (const int*)  d_in[2];
    const float* Wemb  = (const float*)d_in[5];
    const float* bemb  = (const float*)d_in[6];
    const float* Wconv = (const float*)d_in[7];
    const float* bconv = (const float*)d_in[8];
    const float* Wm0   = (const float*)d_in[9];
    const float* bm0   = (const float*)d_in[10];
    const float* Wm1   = (const float*)d_in[11];
    const float* bm1   = (const float*)d_in[12];
    const float* Wm2   = (const float*)d_in[13];
    const float* bm2   = (const float*)d_in[14];
    float* out = (float*)d_out;

    char* ws = (char*)d_ws;
    size_t off = 0;
    auto alloc = [&](size_t bytes) -> void* {
        void* p = ws + off;
        off = (off + bytes + 255) & ~(size_t)255;
        return p;
    };
    unsigned short* h0bf = (unsigned short*)alloc((size_t)NN * 128 * 2);
    unsigned short* h1bf = (unsigned short*)alloc((size_t)NN * 128 * 2);
    unsigned short* cbf  = (unsigned short*)alloc((size_t)NN * 128 * 2);
    unsigned short* pqb  = (unsigned short*)alloc((size_t)NN * 256 * 2);
    unsigned short* xbf  = (unsigned short*)alloc((size_t)NN * 64 * 2);
    unsigned short* Wct   = (unsigned short*)alloc(4 * 128 * 256 * 2);
    unsigned short* Wefft = (unsigned short*)alloc(256 * 128 * 2);
    float*          beff  = (float*)alloc(256 * 4);
    unsigned short* W1tg  = (unsigned short*)alloc(64 * 128 * 2);
    unsigned short* Wembt = (unsigned short*)alloc(128 * 64 * 2);
    int*   deg  = (int*)alloc((size_t)NN * 4);
    int*   rp   = (int*)alloc((size_t)(NN + 1) * 4);
    int*   cnt  = (int*)alloc((size_t)NN * 4);
    float* invd = (float*)alloc((size_t)NN * 4);
    int*   bsum = (int*)alloc(512);
    int4*  pk   = (int4*)alloc((size_t)NE * 16);
    (void)ws_size; (void)in_sizes; (void)n_in; (void)out_size;

    hipMemsetAsync(deg, 0, (size_t)NN * 4, stream);
    hipMemsetAsync(cnt, 0, (size_t)NN * 4, stream);

    // cast x -> bf16; weight prep
    cast_k<<<(NN * 64 / 8 + 255) / 256, 256, 0, stream>>>(x, xbf, NN * 64 / 8);
    prep_k<<<(180480 + 255) / 256, 256, 0, stream>>>(
        Wconv, Wm0, bm0, Wm1, Wemb, Wct, Wefft, beff, W1tg, Wembt);

    // CSR build (packed)
    deg_k  <<<(NE + 255) / 256, 256, 0, stream>>>(edst, deg);
    scan1_k<<<(NN + 511) / 512, 512, 0, stream>>>(deg, rp, bsum);
    scan2_k<<<1, 128, 0, stream>>>(bsum, (NN + 511) / 512);
    scan3_k<<<(NN + 511) / 512, 512, 0, stream>>>(rp, bsum, deg, invd);
    fill_k <<<(NE + 255) / 256, 256, 0, stream>>>(esrc, edst, rp, cnt, pk);

    // h0 = bf16(x @ Wemb + bemb) via MFMA
    mfma_gemm_k<EPI_PQBF><<<dim3((NN + 63) / 64, 1), 256, 0, stream>>>(
        xbf, nullptr, 64, 1 << 30, Wembt, bemb, h0bf, 128, nullptr, NN, 64);

    // 4 SAGE layers (MFMA, bf16 residual)
    unsigned short* hcbf = h0bf; unsigned short* hnbf = h1bf;
    for (int l = 0; l < 4; ++l) {
        agg_k<<<(NN + 3) / 4, 256, 0, stream>>>(hcbf, rp, pk, invd, cbf);
        mfma_gemm_k<EPI_LAYER><<<dim3((NN + 63) / 64, 1), 256, 0, stream>>>(
            hcbf, cbf, 128, 128, Wct + (size_t)l * 128 * 256,
            bconv + (size_t)l * 128, hnbf, 128, hcbf, NN, 256);
        unsigned short* tb = hcbf; hcbf = hnbf; hnbf = tb;
    }
    // after 4 layers: hcbf == h0bf

    // pq = bf16(h @ Weff + beff)  [NN][256]
    mfma_gemm_k<EPI_PQBF><<<dim3((NN + 63) / 64, 2), 256, 0, stream>>>(
        hcbf, nullptr, 128, 1 << 30, Wefft, beff, pqb, 256, nullptr, NN, 128);

    // fused edge readout (CSR order, 128 edges/block, single barrier)
    edge_mlp_k<<<NE / 128, 256, 0, stream>>>(pqb, pk, W1tg, bm1, Wm2, bm2, out);
}

// Round 7
// 489.238 us; speedup vs baseline: 2.1868x; 1.0507x over previous
//
#include <hip/hip_runtime.h>

constexpr int NN  = 50000;   // nodes
constexpr int NE  = 800000;  // edges

using frag_ab = __attribute__((ext_vector_type(8))) short;  // 8 bf16
using frag_cd = __attribute__((ext_vector_type(4))) float;  // 4 fp32

__device__ __forceinline__ unsigned short f2bf(float f) {   // RNE
    union { float f; unsigned u; } v; v.f = f;
    unsigned r = v.u + 0x7FFFu + ((v.u >> 16) & 1u);
    return (unsigned short)(r >> 16);
}
__device__ __forceinline__ float bflo(unsigned u) {
    union { unsigned u; float f; } v; v.u = u << 16; return v.f;
}
__device__ __forceinline__ float bfhi(unsigned u) {
    union { unsigned u; float f; } v; v.u = u & 0xFFFF0000u; return v.f;
}
__device__ __forceinline__ float bfs(unsigned short u) {
    union { unsigned u; float f; } v; v.u = (unsigned)u << 16; return v.f;
}
__device__ __forceinline__ unsigned packbf(float a, float b) {       // RNE
    return (unsigned)f2bf(a) | ((unsigned)f2bf(b) << 16);
}
__device__ __forceinline__ unsigned packbf_fast(float a, float b) {  // round-half-up
    union { float f; unsigned u; } ua, ub; ua.f = a; ub.f = b;
    return ((ua.u + 0x8000u) >> 16) | ((ub.u + 0x8000u) & 0xFFFF0000u);
}

enum { EPI_LAYER = 1, EPI_PQBF = 2 };

// ---------------------------------------------------------------------------
// MFMA bf16 GEMM. Block: 64 rows x 128 cols, 4 waves, BK=64.
// ---------------------------------------------------------------------------
template<int EPI>
__launch_bounds__(256, 4)
__global__ void mfma_gemm_k(const unsigned short* __restrict__ A0,
                            const unsigned short* __restrict__ A1,
                            int lda, int kSplit,
                            const unsigned short* __restrict__ Wt,
                            const float* __restrict__ bias,
                            unsigned short* __restrict__ Cbf, int ldc,
                            const unsigned short* __restrict__ residbf,
                            int M, int K)
{
    __shared__ __align__(16) unsigned short As[64][72];    // [row][k], pad 8
    __shared__ __align__(16) unsigned short Ws[128][72];   // [n][k],  pad 8
    __shared__ float bs[128];
    __shared__ float part[(EPI == EPI_LAYER) ? 64 : 1][17];
    __shared__ float rinv[(EPI == EPI_LAYER) ? 64 : 1];

    const int t  = threadIdx.x;
    const int by = blockIdx.y;
    Wt   += (size_t)by * 128 * K;
    bias += (size_t)by * 128;
    if constexpr (EPI == EPI_PQBF) Cbf += (size_t)by * 128;
    const int m0 = blockIdx.x * 64;

    if (t < 128) bs[t] = bias[t];

    const int wv = t >> 6, l = t & 63, lq = l >> 4, lm = l & 15;
    frag_cd acc[8];
#pragma unroll
    for (int tb = 0; tb < 8; ++tb) acc[tb] = (frag_cd){0.f, 0.f, 0.f, 0.f};

    for (int kt = 0; kt < K; kt += 64) {
        const unsigned short* Asrc = (kt < kSplit) ? A0 : A1;
        const int kcol = (kt < kSplit) ? kt : kt - kSplit;
#pragma unroll
        for (int p = 0; p < 2; ++p) {
            int idx = p * 256 + t;            // 512 uint4 = 64 x 64 bf16
            int row = idx >> 3, c4 = idx & 7;
            int gm = m0 + row;
            uint4 v = make_uint4(0, 0, 0, 0);
            if (gm < M) v = *(const uint4*)&Asrc[(size_t)gm * lda + kcol + c4 * 8];
            *(uint4*)&As[row][c4 * 8] = v;
        }
#pragma unroll
        for (int p = 0; p < 4; ++p) {
            int idx = p * 256 + t;            // 1024 uint4 = 128 x 64 bf16
            int n = idx >> 3, c4 = idx & 7;
            *(uint4*)&Ws[n][c4 * 8] = *(const uint4*)&Wt[(size_t)n * K + kt + c4 * 8];
        }
        __syncthreads();
#pragma unroll
        for (int kb = 0; kb < 2; ++kb) {
            frag_ab af = *(const frag_ab*)&As[wv * 16 + lm][kb * 32 + lq * 8];
#pragma unroll
            for (int tb = 0; tb < 8; ++tb) {
                frag_ab bf = *(const frag_ab*)&Ws[tb * 16 + lm][kb * 32 + lq * 8];
                acc[tb] = __builtin_amdgcn_mfma_f32_16x16x32_bf16(af, bf, acc[tb], 0, 0, 0);
            }
        }
        __syncthreads();
    }

    if constexpr (EPI == EPI_LAYER) {
        float sq[4] = {0.f, 0.f, 0.f, 0.f};
#pragma unroll
        for (int tb = 0; tb < 8; ++tb) {
            float b = bs[tb * 16 + lm];
#pragma unroll
            for (int r = 0; r < 4; ++r) {
                acc[tb][r] += b;
                sq[r] += acc[tb][r] * acc[tb][r];
            }
        }
#pragma unroll
        for (int r = 0; r < 4; ++r) part[wv * 16 + lq * 4 + r][lm] = sq[r];
        __syncthreads();
        if (t < 64) {
            float s = 0.f;
#pragma unroll
            for (int c = 0; c < 16; ++c) s += part[t][c];
            rinv[t] = 1.0f / fmaxf(sqrtf(s), 1e-12f);
        }
        __syncthreads();
#pragma unroll
        for (int r = 0; r < 4; ++r) {
            int gr = m0 + wv * 16 + lq * 4 + r;
            if (gr >= M) continue;
            float ri = rinv[wv * 16 + lq * 4 + r];
#pragma unroll
            for (int tb = 0; tb < 8; ++tb) {
                int col = tb * 16 + lm;
                float o = bfs(residbf[(size_t)gr * 128 + col]) +
                          fmaxf(acc[tb][r], 0.f) * ri;
                Cbf[(size_t)gr * 128 + col] = f2bf(o);
            }
        }
    } else {
#pragma unroll
        for (int r = 0; r < 4; ++r) {
            int gr = m0 + wv * 16 + lq * 4 + r;
            if (gr >= M) continue;
#pragma unroll
            for (int tb = 0; tb < 8; ++tb) {
                int col = tb * 16 + lm;
                Cbf[(size_t)gr * ldc + col] = f2bf(acc[tb][r] + bs[col]);
            }
        }
    }
}

// ---------------------------------------------------------------------------
// x -> bf16 cast (embed input)
// ---------------------------------------------------------------------------
__global__ void cast_k(const float* __restrict__ x, unsigned short* __restrict__ xbf,
                       int n8) {
    int i = blockIdx.x * 256 + threadIdx.x;
    if (i >= n8) return;
    float4 a = *(const float4*)&x[(size_t)i * 8];
    float4 b = *(const float4*)&x[(size_t)i * 8 + 4];
    uint4 o = make_uint4(packbf(a.x, a.y), packbf(a.z, a.w),
                         packbf(b.x, b.y), packbf(b.z, b.w));
    *(uint4*)&xbf[(size_t)i * 8] = o;
}

// ---------------------------------------------------------------------------
// CSR construction -> packed pk[pos]={src,dst,eid,0} + compact srt[pos]=src
// ---------------------------------------------------------------------------
__global__ void deg_k(const int* __restrict__ dst, int* __restrict__ deg) {
    int e = blockIdx.x * 256 + threadIdx.x;
    if (e < NE) atomicAdd(&deg[dst[e]], 1);
}

__global__ void scan1_k(const int* __restrict__ deg, int* __restrict__ rp,
                        int* __restrict__ bsum) {
    __shared__ int sh[512];
    int tid = threadIdx.x;
    int i = blockIdx.x * 512 + tid;
    int v = (i < NN) ? deg[i] : 0;
    sh[tid] = v;
    __syncthreads();
    for (int ofs = 1; ofs < 512; ofs <<= 1) {
        int x = (tid >= ofs) ? sh[tid - ofs] : 0;
        __syncthreads();
        sh[tid] += x;
        __syncthreads();
    }
    if (i < NN) rp[i] = sh[tid] - v;
    if (tid == 511) bsum[blockIdx.x] = sh[511];
}

__global__ void scan2_k(int* __restrict__ bsum, int nb) {
    __shared__ int sh[128];
    int tid = threadIdx.x;
    int v = (tid < nb) ? bsum[tid] : 0;
    sh[tid] = v;
    __syncthreads();
    for (int ofs = 1; ofs < 128; ofs <<= 1) {
        int x = (tid >= ofs) ? sh[tid - ofs] : 0;
        __syncthreads();
        sh[tid] += x;
        __syncthreads();
    }
    if (tid < nb) bsum[tid] = sh[tid] - v;
}

__global__ void scan3_k(int* __restrict__ rp, const int* __restrict__ bsum,
                        const int* __restrict__ deg, float* __restrict__ invd) {
    int i = blockIdx.x * 512 + threadIdx.x;
    if (i < NN) {
        rp[i] += bsum[blockIdx.x];
        int d = deg[i];
        invd[i] = 1.0f / (float)(d > 1 ? d : 1);
    }
    if (i == NN) rp[NN] = NE;
}

__global__ void fill_k(const int* __restrict__ src, const int* __restrict__ dst,
                       const int* __restrict__ rp, int* __restrict__ cnt,
                       int4* __restrict__ pk, int* __restrict__ srt) {
    int e = blockIdx.x * 256 + threadIdx.x;
    if (e < NE) {
        int s = src[e];
        int d = dst[e];
        int pos = rp[d] + atomicAdd(&cnt[d], 1);
        pk[pos]  = make_int4(s, d, e, 0);
        srt[pos] = s;
    }
}

// ---------------------------------------------------------------------------
// Mean aggregation, one WAVE per node. Lane layout: 32 lanes x 8 B per row,
// wave halves process alternating neighbor rows => 1 VMEM instr / 2 rows,
// 4-pair unroll => 8 rows in flight. Halves combined via shfl_xor(32).
// ---------------------------------------------------------------------------
__launch_bounds__(256, 8)
__global__ void agg_k(const unsigned short* __restrict__ hbf,
                      const int* __restrict__ rp, const int* __restrict__ srt,
                      const float* __restrict__ invd,
                      unsigned short* __restrict__ cbf) {
    int gw   = (blockIdx.x * 256 + threadIdx.x) >> 6;   // node = global wave id
    if (gw >= NN) return;
    const int lane = threadIdx.x & 63;
    const int half = lane >> 5;          // which neighbor of the pair
    const int hl   = lane & 31;          // feature group: 4 feats (8 B)
    const int b = rp[gw], e = rp[gw + 1];
    float a0 = 0.f, a1 = 0.f, a2 = 0.f, a3 = 0.f;

    int p = b;
    for (; p + 8 <= e; p += 8) {         // 4 pairs, 8 rows in flight
        int s0 = srt[p     + half];
        int s1 = srt[p + 2 + half];
        int s2 = srt[p + 4 + half];
        int s3 = srt[p + 6 + half];
        uint2 u0 = *(const uint2*)&hbf[(size_t)s0 * 128 + hl * 4];
        uint2 u1 = *(const uint2*)&hbf[(size_t)s1 * 128 + hl * 4];
        uint2 u2 = *(const uint2*)&hbf[(size_t)s2 * 128 + hl * 4];
        uint2 u3 = *(const uint2*)&hbf[(size_t)s3 * 128 + hl * 4];
        a0 += bflo(u0.x) + bflo(u1.x) + bflo(u2.x) + bflo(u3.x);
        a1 += bfhi(u0.x) + bfhi(u1.x) + bfhi(u2.x) + bfhi(u3.x);
        a2 += bflo(u0.y) + bflo(u1.y) + bflo(u2.y) + bflo(u3.y);
        a3 += bfhi(u0.y) + bfhi(u1.y) + bfhi(u2.y) + bfhi(u3.y);
    }
    for (; p + 2 <= e; p += 2) {         // single pair
        int s = srt[p + half];
        uint2 u = *(const uint2*)&hbf[(size_t)s * 128 + hl * 4];
        a0 += bflo(u.x); a1 += bfhi(u.x);
        a2 += bflo(u.y); a3 += bfhi(u.y);
    }
    if (p < e && half == 0) {            // odd-degree tail (half 0 only)
        int s = srt[p];
        uint2 u = *(const uint2*)&hbf[(size_t)s * 128 + hl * 4];
        a0 += bflo(u.x); a1 += bfhi(u.x);
        a2 += bflo(u.y); a3 += bfhi(u.y);
    }
    // combine halves
    a0 += __shfl_xor(a0, 32, 64);
    a1 += __shfl_xor(a1, 32, 64);
    a2 += __shfl_xor(a2, 32, 64);
    a3 += __shfl_xor(a3, 32, 64);

    float iv = invd[gw];
    if (half == 0) {
        uint2 r = make_uint2(packbf(a0 * iv, a1 * iv), packbf(a2 * iv, a3 * iv));
        *(uint2*)&cbf[(size_t)gw * 128 + hl * 4] = r;
    }
}

// ---------------------------------------------------------------------------
// Prep: Wct[4][128n][256k]; Wefft[256n][128k]; W1tg[64n][128k]; beff; Wembt.
// ---------------------------------------------------------------------------
__global__ void prep_k(const float* __restrict__ Wconv, const float* __restrict__ W0,
                       const float* __restrict__ b0, const float* __restrict__ W1,
                       const float* __restrict__ Wemb,
                       unsigned short* __restrict__ Wct,
                       unsigned short* __restrict__ Wefft,
                       float* __restrict__ beff, unsigned short* __restrict__ W1tg,
                       unsigned short* __restrict__ Wembt) {
    int i = blockIdx.x * 256 + threadIdx.x;
    if (i < 131072) {
        int lyr = i >> 15, r = i & 32767, n = r >> 8, k = r & 255;
        Wct[i] = f2bf(Wconv[(size_t)lyr * 32768 + k * 128 + n]);
    } else if (i < 163840) {
        int j = i - 131072, n = j >> 7, k = j & 127;
        float v = (n < 128) ? W0[k * 128 + n] : W0[(128 + k) * 128 + (n - 128)];
        Wefft[j] = f2bf(v);
    } else if (i < 172032) {
        int j = i - 163840, n = j >> 7, k = j & 127;
        W1tg[j] = f2bf(W1[k * 64 + n]);
    } else if (i < 172288) {
        int j = i - 172032;
        beff[j] = (j < 128) ? b0[j] : 0.f;
    } else if (i < 180480) {
        int j = i - 172288, n = j >> 6, k = j & 63;
        Wembt[j] = f2bf(Wemb[k * 128 + n]);
    }
}

// ---------------------------------------------------------------------------
// Fused edge readout (MFMA), CSR order, 64 edges/block, single barrier,
// in-register MLP2 (shfl reduce). LDS 35 KB -> 4 blocks/CU.
// ---------------------------------------------------------------------------
__launch_bounds__(256, 4)
__global__ void edge_mlp_k(const unsigned short* __restrict__ pq,
                           const int4* __restrict__ pk,
                           const unsigned short* __restrict__ W1tg,
                           const float* __restrict__ b1,
                           const float* __restrict__ W2, const float* __restrict__ b2,
                           float* __restrict__ out)
{
    __shared__ __align__(16) unsigned short E0s[64][136];  // 17408 B
    __shared__ __align__(16) unsigned short W1s[64][136];  // 17408 B
    __shared__ int ee[64];
    const int t = threadIdx.x;
    const int p0 = blockIdx.x * 64;

    // stage W1: 64 rows x 128 ushorts = 1024 uint4 (4 per thread)
#pragma unroll
    for (int p = 0; p < 4; ++p) {
        int i4 = p * 256 + t;                 // 0..1023
        int row = i4 >> 4;                    // /16 uint4 per row -> 0..63
        int c4  = i4 & 15;                    // uint4 within row
        *(uint4*)&W1s[row][c4 * 8] = ((const uint4*)W1tg)[i4];
    }

    // phase 1: e0 = relu(p[src] + q[dst]) -> E0s bf16 (4 threads/edge)
    {
        const int ei = t >> 2;
        const int fs = (t & 3) * 32;
        int4 pkv = pk[p0 + ei];
        if ((t & 3) == 0) ee[ei] = pkv.z;
        const unsigned short* pr = pq + (size_t)pkv.x * 256 + fs;
        const unsigned short* qr = pq + (size_t)pkv.y * 256 + 128 + fs;
#pragma unroll
        for (int j = 0; j < 4; ++j) {
            uint4 a = *(const uint4*)(pr + j * 8);
            uint4 b = *(const uint4*)(qr + j * 8);
            uint4 r;
            r.x = packbf_fast(fmaxf(bflo(a.x) + bflo(b.x), 0.f),
                              fmaxf(bfhi(a.x) + bfhi(b.x), 0.f));
            r.y = packbf_fast(fmaxf(bflo(a.y) + bflo(b.y), 0.f),
                              fmaxf(bfhi(a.y) + bfhi(b.y), 0.f));
            r.z = packbf_fast(fmaxf(bflo(a.z) + bflo(b.z), 0.f),
                              fmaxf(bfhi(a.z) + bfhi(b.z), 0.f));
            r.w = packbf_fast(fmaxf(bflo(a.w) + bflo(b.w), 0.f),
                              fmaxf(bfhi(a.w) + bfhi(b.w), 0.f));
            *(uint4*)&E0s[ei][fs + j * 8] = r;
        }
    }
    __syncthreads();                 // single barrier

    // phase 2: MFMA. wave wv: edges [16wv,16wv+16) x 64 outs.
    const int wv = t >> 6, l = t & 63, lq = l >> 4, lm = l & 15;
    frag_cd acc[4];
#pragma unroll
    for (int tb = 0; tb < 4; ++tb) acc[tb] = (frag_cd){0.f, 0.f, 0.f, 0.f};
    const int erow = wv * 16 + lm;
#pragma unroll
    for (int kb = 0; kb < 4; ++kb) {
        frag_ab af = *(const frag_ab*)&E0s[erow][kb * 32 + lq * 8];
#pragma unroll
        for (int tb = 0; tb < 4; ++tb) {
            frag_ab bf = *(const frag_ab*)&W1s[tb * 16 + lm][kb * 32 + lq * 8];
            acc[tb] = __builtin_amdgcn_mfma_f32_16x16x32_bf16(af, bf, acc[tb], 0, 0, 0);
        }
    }

    // phase 3: in-register MLP2 (b1/W2 direct from global, L2-resident)
    float b1v[4], w20[4], w21[4];
#pragma unroll
    for (int tb = 0; tb < 4; ++tb) {
        int o = tb * 16 + lm;
        b1v[tb] = b1[o];
        w20[tb] = W2[o * 2];
        w21[tb] = W2[o * 2 + 1];
    }
    const float bo0 = b2[0], bo1 = b2[1];
#pragma unroll
    for (int r = 0; r < 4; ++r) {
        float s0 = 0.f, s1 = 0.f;
#pragma unroll
        for (int tb = 0; tb < 4; ++tb) {
            float e1 = fmaxf(acc[tb][r] + b1v[tb], 0.f);
            s0 += e1 * w20[tb];
            s1 += e1 * w21[tb];
        }
#pragma unroll
        for (int m = 1; m < 16; m <<= 1) {   // reduce over lm
            s0 += __shfl_xor(s0, m, 16);
            s1 += __shfl_xor(s1, m, 16);
        }
        if (lm == 0) {
            int e = wv * 16 + lq * 4 + r;
            *(float2*)&out[(size_t)ee[e] * 2] = make_float2(s0 + bo0, s1 + bo1);
        }
    }
}

// ---------------------------------------------------------------------------
extern "C" void kernel_launch(void* const* d_in, const int* in_sizes, int n_in,
                              void* d_out, int out_size, void* d_ws, size_t ws_size,
                              hipStream_t stream)
{
    const float* x    = (const float*)d_in[0];
    const int*   esrc = (const int*)  d_in[1];
    const int*   edst = (const int*)  d_in[2];
    const float* Wemb  = (const float*)d_in[5];
    const float* bemb  = (const float*)d_in[6];
    const float* Wconv = (const float*)d_in[7];
    const float* bconv = (const float*)d_in[8];
    const float* Wm0   = (const float*)d_in[9];
    const float* bm0   = (const float*)d_in[10];
    const float* Wm1   = (const float*)d_in[11];
    const float* bm1   = (const float*)d_in[12];
    const float* Wm2   = (const float*)d_in[13];
    const float* bm2   = (const float*)d_in[14];
    float* out = (float*)d_out;

    char* ws = (char*)d_ws;
    size_t off = 0;
    auto alloc = [&](size_t bytes) -> void* {
        void* p = ws + off;
        off = (off + bytes + 255) & ~(size_t)255;
        return p;
    };
    unsigned short* h0bf = (unsigned short*)alloc((size_t)NN * 128 * 2);
    unsigned short* h1bf = (unsigned short*)alloc((size_t)NN * 128 * 2);
    unsigned short* cbf  = (unsigned short*)alloc((size_t)NN * 128 * 2);
    unsigned short* pqb  = (unsigned short*)alloc((size_t)NN * 256 * 2);
    unsigned short* xbf  = (unsigned short*)alloc((size_t)NN * 64 * 2);
    unsigned short* Wct   = (unsigned short*)alloc(4 * 128 * 256 * 2);
    unsigned short* Wefft = (unsigned short*)alloc(256 * 128 * 2);
    float*          beff  = (float*)alloc(256 * 4);
    unsigned short* W1tg  = (unsigned short*)alloc(64 * 128 * 2);
    unsigned short* Wembt = (unsigned short*)alloc(128 * 64 * 2);
    int*   deg  = (int*)alloc((size_t)NN * 4);
    int*   rp   = (int*)alloc((size_t)(NN + 1) * 4);
    int*   cnt  = (int*)alloc((size_t)NN * 4);
    float* invd = (float*)alloc((size_t)NN * 4);
    int*   bsum = (int*)alloc(512);
    int4*  pk   = (int4*)alloc((size_t)NE * 16);
    int*   srt  = (int*)alloc((size_t)NE * 4);
    (void)ws_size; (void)in_sizes; (void)n_in; (void)out_size;

    hipMemsetAsync(deg, 0, (size_t)NN * 4, stream);
    hipMemsetAsync(cnt, 0, (size_t)NN * 4, stream);

    // cast x -> bf16; weight prep
    cast_k<<<(NN * 64 / 8 + 255) / 256, 256, 0, stream>>>(x, xbf, NN * 64 / 8);
    prep_k<<<(180480 + 255) / 256, 256, 0, stream>>>(
        Wconv, Wm0, bm0, Wm1, Wemb, Wct, Wefft, beff, W1tg, Wembt);

    // CSR build (packed + compact srt)
    deg_k  <<<(NE + 255) / 256, 256, 0, stream>>>(edst, deg);
    scan1_k<<<(NN + 511) / 512, 512, 0, stream>>>(deg, rp, bsum);
    scan2_k<<<1, 128, 0, stream>>>(bsum, (NN + 511) / 512);
    scan3_k<<<(NN + 511) / 512, 512, 0, stream>>>(rp, bsum, deg, invd);
    fill_k <<<(NE + 255) / 256, 256, 0, stream>>>(esrc, edst, rp, cnt, pk, srt);

    // h0 = bf16(x @ Wemb + bemb) via MFMA
    mfma_gemm_k<EPI_PQBF><<<dim3((NN + 63) / 64, 1), 256, 0, stream>>>(
        xbf, nullptr, 64, 1 << 30, Wembt, bemb, h0bf, 128, nullptr, NN, 64);

    // 4 SAGE layers (MFMA, bf16 residual)
    unsigned short* hcbf = h0bf; unsigned short* hnbf = h1bf;
    for (int l = 0; l < 4; ++l) {
        agg_k<<<(NN + 3) / 4, 256, 0, stream>>>(hcbf, rp, srt, invd, cbf);
        mfma_gemm_k<EPI_LAYER><<<dim3((NN + 63) / 64, 1), 256, 0, stream>>>(
            hcbf, cbf, 128, 128, Wct + (size_t)l * 128 * 256,
            bconv + (size_t)l * 128, hnbf, 128, hcbf, NN, 256);
        unsigned short* tb = hcbf; hcbf = hnbf; hnbf = tb;
    }
    // after 4 layers: hcbf == h0bf

    // pq = bf16(h @ Weff + beff)  [NN][256]
    mfma_gemm_k<EPI_PQBF><<<dim3((NN + 63) / 64, 2), 256, 0, stream>>>(
        hcbf, nullptr, 128, 1 << 30, Wefft, beff, pqb, 256, nullptr, NN, 128);

    // fused edge readout (CSR order, 64 edges/block, single barrier)
    edge_mlp_k<<<NE / 64, 256, 0, stream>>>(pqb, pk, W1tg, bm1, Wm2, bm2, out);
}